// Round 6
// baseline (955.048 us; speedup 1.0000x reference)
//
#include <hip/hip_runtime.h>
#include <hip/hip_fp16.h>
#include <math.h>
#include <type_traits>

typedef _Float16 half8 __attribute__((ext_vector_type(8)));
typedef float floatx4 __attribute__((ext_vector_type(4)));

#define CC 16          // column chunks (power of 2, stride for rowptr2)
#define RSHIFT 9       // rows per bucket = 512 (pass B/C)

// ---------------- degree count per (row, col-chunk) ----------------
__global__ void deg_count_kernel(const int* __restrict__ row, const int* __restrict__ col,
                                 int* __restrict__ degi2, int E, int cshift) {
    int g = blockIdx.x * blockDim.x + threadIdx.x;
    if (g < E) atomicAdd(&degi2[row[g] * CC + (col[g] >> cshift)], 1);
}

// ---------------- per-node GSO coefficients ----------------
__device__ __forceinline__ float pow_z(float d, float e) {
    float p = powf(d, e);
    return isinf(p) ? 0.0f : p;   // reference zeroes inf from 0**negative
}

__global__ void node_coeff_kernel(const int* __restrict__ rowptr2,
                                  const float* __restrict__ p1, const float* __restrict__ p2,
                                  float4* __restrict__ coeff, float* __restrict__ wself, int N) {
    int g = blockIdx.x * blockDim.x + threadIdx.x;
    if (g >= N) return;
    float deg = (float)(rowptr2[(size_t)(g + 1) * CC] - rowptr2[(size_t)g * CC]);
    float m1a = p1[0], m2a = p1[1], m3a = p1[2], e1a = p1[3], e2a = p1[4], e3a = p1[5], aa = p1[6];
    float m1b = p2[0], m2b = p2[1], m3b = p2[2], e1b = p2[3], e2b = p2[4], e3b = p2[5], ab = p2[6];
    float d1 = deg + aa, d2 = deg + ab;
    float pa1 = pow_z(d1, e1a), pa2 = pow_z(d1, e2a), pa3 = pow_z(d1, e3a);
    float pb1 = pow_z(d2, e1b), pb2 = pow_z(d2, e2b), pb3 = pow_z(d2, e3b);
    coeff[g] = make_float4(m2a * pa2, pa3, m2b * pb2, pb3);
    wself[g] = m1a * pa1 + m2a * pa2 * pa3 + m3a
             + m1b * pb1 + m2b * pb2 * pb3 + m3b;
}

// ---------------- scan (3 kernels) over n2 = N*CC entries ----------------
__global__ void scan_block_kernel(const int* __restrict__ degi, int* __restrict__ rowptr,
                                  int* __restrict__ blocksum, int n) {
    __shared__ int sums[256];
    int tid = threadIdx.x;
    int base = blockIdx.x * 1024 + tid * 4;
    int d0 = (base + 0 < n) ? degi[base + 0] : 0;
    int d1 = (base + 1 < n) ? degi[base + 1] : 0;
    int d2 = (base + 2 < n) ? degi[base + 2] : 0;
    int d3 = (base + 3 < n) ? degi[base + 3] : 0;
    int s0 = d0, s1 = s0 + d1, s2 = s1 + d2, s3 = s2 + d3;
    sums[tid] = s3;
    __syncthreads();
    for (int off = 1; off < 256; off <<= 1) {
        int v = (tid >= off) ? sums[tid - off] : 0;
        __syncthreads();
        sums[tid] += v;
        __syncthreads();
    }
    int excl = sums[tid] - s3;
    if (base + 0 < n) rowptr[base + 1] = excl + s0;
    if (base + 1 < n) rowptr[base + 2] = excl + s1;
    if (base + 2 < n) rowptr[base + 3] = excl + s2;
    if (base + 3 < n) rowptr[base + 4] = excl + s3;
    if (tid == 255) blocksum[blockIdx.x] = sums[255];
}

// capacity 2048 block sums (8 per thread, serial + block scan)
__global__ void scan_tops_kernel(const int* __restrict__ blocksum, int* __restrict__ blockoff, int nb) {
    __shared__ int s[256];
    int tid = threadIdx.x;
    int loc[8]; int tot = 0;
#pragma unroll
    for (int u = 0; u < 8; ++u) {
        int i = tid * 8 + u;
        loc[u] = (i < nb) ? blocksum[i] : 0;
        tot += loc[u];
    }
    s[tid] = tot;
    __syncthreads();
    for (int off = 1; off < 256; off <<= 1) {
        int v = (tid >= off) ? s[tid - off] : 0;
        __syncthreads();
        s[tid] += v;
        __syncthreads();
    }
    int excl = s[tid] - tot;
#pragma unroll
    for (int u = 0; u < 8; ++u) {
        int i = tid * 8 + u;
        if (i < nb) blockoff[i] = excl;
        excl += loc[u];
    }
}

__global__ void scan_add_kernel(int* __restrict__ rowptr, const int* __restrict__ blockoff, int n) {
    int g = blockIdx.x * blockDim.x + threadIdx.x;
    if (g == 0) rowptr[0] = 0;
    if (g < n) rowptr[g + 1] += blockoff[g >> 10];
}

// ---------------- pass B: radix partition edges by row-bucket ----------------
__global__ __launch_bounds__(256) void partition_kernel(
        const int* __restrict__ row, const int* __restrict__ col,
        const int* __restrict__ rowptr2, int* __restrict__ gcur,
        const float4* __restrict__ coeff, int2* __restrict__ epack_mid,
        int E, int NB) {
    __shared__ int scnt[256], sofs[256], scur[256], gslot[256];
    __shared__ int2 sdata[4096];
    __shared__ unsigned short sbkt[4096];

    int tid = threadIdx.x;
    int base = blockIdx.x * 4096;
    scnt[tid] = 0;
    __syncthreads();

    int epk[16]; float ew[16]; int eb[16];
#pragma unroll
    for (int u = 0; u < 16; ++u) {
        int e = base + u * 256 + tid;
        eb[u] = -1;
        if (e < E) {
            int r = row[e], c = col[e];
            int b = r >> RSHIFT;
            eb[u] = b;
            atomicAdd(&scnt[b], 1);
            float4 cr = coeff[r], cc = coeff[c];
            ew[u] = cr.x * cc.y + cr.z * cc.w;
            epk[u] = c | ((r & ((1 << RSHIFT) - 1)) << 20);
        }
    }
    __syncthreads();
    sofs[tid] = scnt[tid];
    __syncthreads();
    for (int off = 1; off < 256; off <<= 1) {
        int v = (tid >= off) ? sofs[tid - off] : 0;
        __syncthreads();
        sofs[tid] += v;
        __syncthreads();
    }
    int excl = sofs[tid] - scnt[tid];
    sofs[tid] = excl;
    scur[tid] = excl;
    if (tid < NB && scnt[tid] > 0)
        gslot[tid] = rowptr2[(size_t)(tid << RSHIFT) * CC] + atomicAdd(&gcur[tid], scnt[tid]);
    __syncthreads();
#pragma unroll
    for (int u = 0; u < 16; ++u) {
        if (eb[u] >= 0) {
            int idx = atomicAdd(&scur[eb[u]], 1);
            sdata[idx] = make_int2(epk[u], __float_as_int(ew[u]));
            sbkt[idx] = (unsigned short)eb[u];
        }
    }
    __syncthreads();
    int cntR = min(4096, E - base);
    for (int i = tid; i < cntR; i += 256) {
        int b = sbkt[i];
        epack_mid[gslot[b] + (i - sofs[b])] = sdata[i];
    }
}

// ---------------- pass C: place into (row, col-chunk) CSR segments ----------------
__global__ __launch_bounds__(256) void bucket_sort_kernel(
        const int* __restrict__ rowptr2, const int2* __restrict__ epack_mid,
        int2* __restrict__ epack, int N, int cshift) {
    __shared__ int lcur[(1 << RSHIFT) * CC];   // 512*16 = 8192 ints = 32KB
    int b = blockIdx.x;
    int tid = threadIdx.x;
    int rows = 1 << RSHIFT;
    int row0 = b << RSHIFT;
    int nslots = (min(rows, N - row0)) * CC;
    for (int j = tid; j < nslots; j += 256)
        lcur[j] = rowptr2[(size_t)row0 * CC + j];   // contiguous, coalesced
    __syncthreads();
    int slice0 = rowptr2[(size_t)row0 * CC];
    int slice1 = rowptr2[(size_t)min(row0 + rows, N) * CC];
    for (int i = slice0 + tid; i < slice1; i += 256) {
        int2 p = epack_mid[i];
        int colv = p.x & 0xFFFFF;
        int rl = ((unsigned)p.x) >> 20;
        int ch = colv >> cshift;
        int pos = atomicAdd(&lcur[rl * CC + ch], 1);
        epack[pos] = make_int2(colv, p.y);
    }
}

// ---------------- W convert + transpose (one launch) ----------------
__global__ void convert_w_all(const float* __restrict__ W1, const float* __restrict__ W2,
                              const float* __restrict__ W3, _Float16* __restrict__ Wt1,
                              _Float16* __restrict__ Wt2, _Float16* __restrict__ Wt3) {
    int g = blockIdx.x * blockDim.x + threadIdx.x;
    if (g < 16384) {
        int k = g >> 7, n = g & 127;
        Wt1[n * 128 + k] = (_Float16)W1[g];
    } else if (g < 32768) {
        int h = g - 16384; int k = h >> 7, n = h & 127;
        Wt2[n * 128 + k] = (_Float16)W2[h];
    } else if (g < 40960) {
        int h = g - 32768; int k = h >> 6, n = h & 63;
        Wt3[n * 128 + k] = (_Float16)W3[h];
    }
}

// ---------------- MFMA GEMM: A[n x 128] @ W[128 x TN] -> C[n x TN] fp16 ----------------
template<int TN, typename AT>
__global__ __launch_bounds__(256) void gemm_mfma(const AT* __restrict__ A,
        const _Float16* __restrict__ Wt, _Float16* __restrict__ C, int n) {
    constexpr int K = 128;
    constexpr int TM = 64;
    constexpr int LDK = K + 8;
    __shared__ _Float16 As[TM][LDK];
    __shared__ _Float16 Bs[TN][LDK];

    int tid = threadIdx.x;
    int wave = tid >> 6, lane = tid & 63;
    int q = lane >> 4, t = lane & 15;
    int rowbase = blockIdx.x * TM;

    if constexpr (std::is_same<AT, float>::value) {
        for (int i = tid; i < TM * K / 4; i += 256) {
            int r = i >> 5;
            int kc = (i & 31) * 4;
            int rr = rowbase + r;
            float4 v = make_float4(0.f, 0.f, 0.f, 0.f);
            if (rr < n) v = *(const float4*)&A[(size_t)rr * K + kc];
            As[r][kc + 0] = (_Float16)v.x;
            As[r][kc + 1] = (_Float16)v.y;
            As[r][kc + 2] = (_Float16)v.z;
            As[r][kc + 3] = (_Float16)v.w;
        }
    } else {
        for (int i = tid; i < TM * K / 8; i += 256) {
            int r = i >> 4;
            int kc = (i & 15) * 8;
            int rr = rowbase + r;
            uint4 v = make_uint4(0u, 0u, 0u, 0u);
            if (rr < n) v = *(const uint4*)&A[(size_t)rr * K + kc];
            *(uint4*)&As[r][kc] = v;
        }
    }
    for (int i = tid; i < TN * K / 8; i += 256) {
        int nr = i >> 4;
        int kc = (i & 15) * 8;
        *(uint4*)&Bs[nr][kc] = *(const uint4*)&Wt[(size_t)nr * K + kc];
    }
    __syncthreads();

    int m0 = wave * 16;
    floatx4 acc[TN / 16];
#pragma unroll
    for (int nt = 0; nt < TN / 16; ++nt) acc[nt] = (floatx4){0.f, 0.f, 0.f, 0.f};

#pragma unroll
    for (int kk = 0; kk < K; kk += 32) {
        half8 a = *(const half8*)&As[m0 + t][kk + q * 8];
#pragma unroll
        for (int nt = 0; nt < TN / 16; ++nt) {
            half8 b = *(const half8*)&Bs[nt * 16 + t][kk + q * 8];
            acc[nt] = __builtin_amdgcn_mfma_f32_16x16x32_f16(a, b, acc[nt], 0, 0, 0);
        }
    }

#pragma unroll
    for (int nt = 0; nt < TN / 16; ++nt) {
#pragma unroll
        for (int r = 0; r < 4; ++r) {
            int rr = rowbase + m0 + q * 4 + r;
            if (rr < n) C[(size_t)rr * TN + nt * 16 + t] = (_Float16)acc[nt][r];
        }
    }
}

// ---------------- chunked CSR aggregation, D=128 ----------------
// 8 nodes per wave, accumulators in registers; chunk-outer sweep keeps the
// active H slice (~2MB) L2-resident across all concurrently-running waves.
__global__ __launch_bounds__(256) void agg128_kernel(const __half2* __restrict__ H,
        const int* __restrict__ rowptr2, const int2* __restrict__ epack,
        const float* __restrict__ wself, const float* __restrict__ bias,
        __half2* __restrict__ out, int n, int nchunk) {
    int wave = threadIdx.x >> 6, lane = threadIdx.x & 63;
    int node0 = blockIdx.x * 32 + wave * 8;
    if (node0 >= n) return;
    int nv = min(8, n - node0);
    float ax[8], ay[8];
#pragma unroll
    for (int i = 0; i < 8; ++i) { ax[i] = 0.f; ay[i] = 0.f; }
#pragma unroll
    for (int i = 0; i < 8; ++i) {
        if (i < nv) {
            float w = wself[node0 + i];
            float2 h = __half22float2(H[(size_t)(node0 + i) * 64 + lane]);
            ax[i] = w * h.x; ay[i] = w * h.y;
        }
    }
    for (int c = 0; c < nchunk; ++c) {
        int sa[8], ea[8];
#pragma unroll
        for (int i = 0; i < 8; ++i) {
            sa[i] = (i < nv) ? rowptr2[(size_t)(node0 + i) * CC + c] : 0;
            ea[i] = (i < nv) ? rowptr2[(size_t)(node0 + i) * CC + c + 1] : 0;
        }
        for (;;) {
            bool any = false;
            int2 pk[8];
#pragma unroll
            for (int i = 0; i < 8; ++i) {
                if (sa[i] < ea[i]) { pk[i] = epack[sa[i]]; any = true; }
            }
            if (!any) break;
            __half2 hh[8];
#pragma unroll
            for (int i = 0; i < 8; ++i)
                if (sa[i] < ea[i]) hh[i] = H[(size_t)pk[i].x * 64 + lane];
#pragma unroll
            for (int i = 0; i < 8; ++i) {
                if (sa[i] < ea[i]) {
                    float w = __int_as_float(pk[i].y);
                    float2 f = __half22float2(hh[i]);
                    ax[i] += w * f.x; ay[i] += w * f.y;
                    sa[i]++;
                }
            }
        }
    }
    float2 b = *(const float2*)&bias[2 * lane];
#pragma unroll
    for (int i = 0; i < 8; ++i) {
        if (i < nv) {
            float vx = fmaxf(ax[i] + b.x, 0.f);
            float vy = fmaxf(ay[i] + b.y, 0.f);
            out[(size_t)(node0 + i) * 64 + lane] = __floats2half2_rn(vx, vy);
        }
    }
}

// ---------------- chunked CSR aggregation, D=64, fp32 out, no relu ----------------
__global__ __launch_bounds__(256) void agg64_kernel(const __half* __restrict__ H,
        const int* __restrict__ rowptr2, const int2* __restrict__ epack,
        const float* __restrict__ wself, const float* __restrict__ bias,
        float* __restrict__ out, int n, int nchunk) {
    int wave = threadIdx.x >> 6, lane = threadIdx.x & 63;
    int node0 = blockIdx.x * 32 + wave * 8;
    if (node0 >= n) return;
    int nv = min(8, n - node0);
    float acc[8];
#pragma unroll
    for (int i = 0; i < 8; ++i) acc[i] = 0.f;
#pragma unroll
    for (int i = 0; i < 8; ++i) {
        if (i < nv)
            acc[i] = wself[node0 + i] * __half2float(H[(size_t)(node0 + i) * 64 + lane]);
    }
    for (int c = 0; c < nchunk; ++c) {
        int sa[8], ea[8];
#pragma unroll
        for (int i = 0; i < 8; ++i) {
            sa[i] = (i < nv) ? rowptr2[(size_t)(node0 + i) * CC + c] : 0;
            ea[i] = (i < nv) ? rowptr2[(size_t)(node0 + i) * CC + c + 1] : 0;
        }
        for (;;) {
            bool any = false;
            int2 pk[8];
#pragma unroll
            for (int i = 0; i < 8; ++i) {
                if (sa[i] < ea[i]) { pk[i] = epack[sa[i]]; any = true; }
            }
            if (!any) break;
            float f[8];
#pragma unroll
            for (int i = 0; i < 8; ++i)
                if (sa[i] < ea[i]) f[i] = __half2float(H[(size_t)pk[i].x * 64 + lane]);
#pragma unroll
            for (int i = 0; i < 8; ++i) {
                if (sa[i] < ea[i]) {
                    acc[i] += __int_as_float(pk[i].y) * f[i];
                    sa[i]++;
                }
            }
        }
    }
    float b = bias[lane];
#pragma unroll
    for (int i = 0; i < 8; ++i) {
        if (i < nv) out[(size_t)(node0 + i) * 64 + lane] = acc[i] + b;
    }
}

// ---------------- launch ----------------
extern "C" void kernel_launch(void* const* d_in, const int* in_sizes, int n_in,
                              void* d_out, int out_size, void* d_ws, size_t ws_size,
                              hipStream_t stream) {
    const float* x  = (const float*)d_in[0];
    const int*   ei = (const int*)d_in[1];
    const float* W1 = (const float*)d_in[2];
    const float* b1 = (const float*)d_in[3];
    const float* W2 = (const float*)d_in[4];
    const float* b2 = (const float*)d_in[5];
    const float* W3 = (const float*)d_in[6];
    const float* b3 = (const float*)d_in[7];
    const float* p1 = (const float*)d_in[8];
    const float* p2 = (const float*)d_in[9];

    const int N = in_sizes[0] / 128;
    const int E = in_sizes[1] / 2;
    const int* row = ei;
    const int* col = ei + E;

    // column chunk shift: smallest s with ((N-1)>>s) <= CC-1 ; N=100000 -> 13, 13 chunks
    int cshift = 0;
    while (((N - 1) >> cshift) > (CC - 1)) cshift++;
    const int nchunk = ((N - 1) >> cshift) + 1;
    const int NB = ((N - 1) >> RSHIFT) + 1;              // row buckets (196)
    const int n2 = N * CC;                               // rowptr2 entries - 1

    char* p = (char*)d_ws;
    auto alloc = [&](size_t bytes) -> void* {
        void* q = (void*)p;
        p += (bytes + 255) & ~(size_t)255;
        return q;
    };
    int*      degi2     = (int*)alloc((size_t)n2 * 4);
    int*      gcur      = (int*)alloc(256 * 4);          // contiguous with degi2 for one memset
    int*      rowptr2   = (int*)alloc((size_t)(n2 + 1) * 4);
    const int NBLK      = (n2 + 1023) / 1024;            // 1563 <= 2048 scan_tops capacity
    int*      blocksum  = (int*)alloc((size_t)NBLK * 4);
    int*      blockoff  = (int*)alloc((size_t)NBLK * 4);
    float4*   coeff     = (float4*)alloc((size_t)N * 16);
    float*    wself     = (float*)alloc((size_t)N * 4);
    int2*     epack_mid = (int2*)alloc((size_t)E * 8);
    int2*     epack     = (int2*)alloc((size_t)E * 8);
    _Float16* Wt1       = (_Float16*)alloc(128 * 128 * 2);
    _Float16* Wt2       = (_Float16*)alloc(128 * 128 * 2);
    _Float16* Wt3       = (_Float16*)alloc(128 * 64 * 2);
    _Float16* bufH      = (_Float16*)alloc((size_t)N * 128 * 2);
    _Float16* actH      = (_Float16*)alloc((size_t)N * 128 * 2);
    (void)ws_size; (void)n_in;

    size_t zero_bytes = (size_t)((char*)rowptr2 - (char*)degi2);
    hipMemsetAsync(degi2, 0, zero_bytes, stream);

    convert_w_all<<<160, 256, 0, stream>>>(W1, W2, W3, Wt1, Wt2, Wt3);

    deg_count_kernel<<<(E + 255) / 256, 256, 0, stream>>>(row, col, degi2, E, cshift);
    scan_block_kernel<<<NBLK, 256, 0, stream>>>(degi2, rowptr2, blocksum, n2);
    scan_tops_kernel<<<1, 256, 0, stream>>>(blocksum, blockoff, NBLK);
    scan_add_kernel<<<(n2 + 255) / 256, 256, 0, stream>>>(rowptr2, blockoff, n2);
    node_coeff_kernel<<<(N + 255) / 256, 256, 0, stream>>>(rowptr2, p1, p2, coeff, wself, N);
    partition_kernel<<<(E + 4095) / 4096, 256, 0, stream>>>(row, col, rowptr2, gcur, coeff,
                                                            epack_mid, E, NB);
    bucket_sort_kernel<<<NB, 256, 0, stream>>>(rowptr2, epack_mid, epack, N, cshift);

    float* out = (float*)d_out;
    int aggGrid = (N + 31) / 32;
    int gemmGrid = (N + 63) / 64;
    // layer 1
    gemm_mfma<128, float><<<gemmGrid, 256, 0, stream>>>(x, Wt1, bufH, N);
    agg128_kernel<<<aggGrid, 256, 0, stream>>>((const __half2*)bufH, rowptr2, epack, wself,
                                               b1, (__half2*)actH, N, nchunk);
    // layer 2
    gemm_mfma<128, _Float16><<<gemmGrid, 256, 0, stream>>>(actH, Wt2, bufH, N);
    agg128_kernel<<<aggGrid, 256, 0, stream>>>((const __half2*)bufH, rowptr2, epack, wself,
                                               b2, (__half2*)actH, N, nchunk);
    // layer 3 (D_OUT=64, no relu)
    gemm_mfma<64, _Float16><<<gemmGrid, 256, 0, stream>>>(actH, Wt3, bufH, N);
    agg64_kernel<<<aggGrid, 256, 0, stream>>>((const __half*)bufH, rowptr2, epack, wself,
                                              b3, out, N, nchunk);
}

// Round 7
// 535.120 us; speedup vs baseline: 1.7847x; 1.7847x over previous
//
#include <hip/hip_runtime.h>
#include <hip/hip_fp16.h>
#include <math.h>
#include <type_traits>

typedef _Float16 half8 __attribute__((ext_vector_type(8)));
typedef float floatx4 __attribute__((ext_vector_type(4)));

// ---------------- degree count ----------------
__global__ void deg_count_kernel(const int* __restrict__ row, int* __restrict__ degi, int E) {
    int g = blockIdx.x * blockDim.x + threadIdx.x;
    if (g < E) atomicAdd(&degi[row[g]], 1);
}

// ---------------- per-node GSO coefficient helper ----------------
__device__ __forceinline__ float pow_z(float d, float e) {
    float p = powf(d, e);
    return isinf(p) ? 0.0f : p;   // reference zeroes inf from 0**negative
}

__device__ __forceinline__ void gso_coeff(float deg, const float* __restrict__ p1,
                                          const float* __restrict__ p2,
                                          float4* cf, float* ws) {
    float m1a = p1[0], m2a = p1[1], m3a = p1[2], e1a = p1[3], e2a = p1[4], e3a = p1[5], aa = p1[6];
    float m1b = p2[0], m2b = p2[1], m3b = p2[2], e1b = p2[3], e2b = p2[4], e3b = p2[5], ab = p2[6];
    float d1 = deg + aa, d2 = deg + ab;
    float pa1 = pow_z(d1, e1a), pa2 = pow_z(d1, e2a), pa3 = pow_z(d1, e3a);
    float pb1 = pow_z(d2, e1b), pb2 = pow_z(d2, e2b), pb3 = pow_z(d2, e3b);
    *cf = make_float4(m2a * pa2, pa3, m2b * pb2, pb3);
    *ws = m1a * pa1 + m2a * pa2 * pa3 + m3a
        + m1b * pb1 + m2b * pb2 * pb3 + m3b;
}

// ---------------- fused: block scan of degrees + GSO coefficients ----------------
__global__ void scan_block_kernel(const int* __restrict__ degi, int* __restrict__ rowptr,
                                  int* __restrict__ blocksum,
                                  const float* __restrict__ p1, const float* __restrict__ p2,
                                  float4* __restrict__ coeff, float* __restrict__ wself, int n) {
    __shared__ int sums[256];
    int tid = threadIdx.x;
    int base = blockIdx.x * 1024 + tid * 4;
    int d0 = (base + 0 < n) ? degi[base + 0] : 0;
    int d1 = (base + 1 < n) ? degi[base + 1] : 0;
    int d2 = (base + 2 < n) ? degi[base + 2] : 0;
    int d3 = (base + 3 < n) ? degi[base + 3] : 0;
    int s0 = d0, s1 = s0 + d1, s2 = s1 + d2, s3 = s2 + d3;
    sums[tid] = s3;
    __syncthreads();
    for (int off = 1; off < 256; off <<= 1) {
        int v = (tid >= off) ? sums[tid - off] : 0;
        __syncthreads();
        sums[tid] += v;
        __syncthreads();
    }
    int excl = sums[tid] - s3;
    if (base + 0 < n) rowptr[base + 1] = excl + s0;
    if (base + 1 < n) rowptr[base + 2] = excl + s1;
    if (base + 2 < n) rowptr[base + 3] = excl + s2;
    if (base + 3 < n) rowptr[base + 4] = excl + s3;
    if (tid == 255) blocksum[blockIdx.x] = sums[255];
    int dd[4] = {d0, d1, d2, d3};
#pragma unroll
    for (int u = 0; u < 4; ++u) {
        if (base + u < n) {
            float4 cf; float ws;
            gso_coeff((float)dd[u], p1, p2, &cf, &ws);
            coeff[base + u] = cf;
            wself[base + u] = ws;
        }
    }
}

__global__ void scan_tops_kernel(const int* __restrict__ blocksum, int* __restrict__ blockoff, int nb) {
    __shared__ int s[128];
    int tid = threadIdx.x;
    int v = (tid < nb) ? blocksum[tid] : 0;
    s[tid] = v;
    __syncthreads();
    for (int off = 1; off < 128; off <<= 1) {
        int u = (tid >= off) ? s[tid - off] : 0;
        __syncthreads();
        s[tid] += u;
        __syncthreads();
    }
    if (tid < nb) blockoff[tid] = s[tid] - v;
}

__global__ void scan_add_kernel(int* __restrict__ rowptr, const int* __restrict__ blockoff, int n) {
    int g = blockIdx.x * blockDim.x + threadIdx.x;
    if (g == 0) rowptr[0] = 0;
    if (g < n) rowptr[g + 1] += blockoff[g >> 10];
}

// ---------------- pass B: radix partition edges by row-bucket ----------------
__global__ __launch_bounds__(256) void partition_kernel(
        const int* __restrict__ row, const int* __restrict__ col,
        const int* __restrict__ rowptr, int* __restrict__ gcur,
        const float4* __restrict__ coeff, int2* __restrict__ epack_mid,
        int E, int shift, int NB) {
    __shared__ int scnt[256], sofs[256], scur[256], gslot[256];
    __shared__ int2 sdata[4096];
    __shared__ unsigned short sbkt[4096];

    int tid = threadIdx.x;
    int base = blockIdx.x * 4096;
    scnt[tid] = 0;
    __syncthreads();

    int epk[16]; float ew[16]; int eb[16];
#pragma unroll
    for (int u = 0; u < 16; ++u) {
        int e = base + u * 256 + tid;
        eb[u] = -1;
        if (e < E) {
            int r = row[e], c = col[e];
            int b = r >> shift;
            eb[u] = b;
            atomicAdd(&scnt[b], 1);
            float4 cr = coeff[r], cc = coeff[c];
            ew[u] = cr.x * cc.y + cr.z * cc.w;
            epk[u] = c | ((r & ((1 << shift) - 1)) << 20);
        }
    }
    __syncthreads();
    sofs[tid] = scnt[tid];
    __syncthreads();
    for (int off = 1; off < 256; off <<= 1) {
        int v = (tid >= off) ? sofs[tid - off] : 0;
        __syncthreads();
        sofs[tid] += v;
        __syncthreads();
    }
    int excl = sofs[tid] - scnt[tid];
    sofs[tid] = excl;
    scur[tid] = excl;
    if (tid < NB && scnt[tid] > 0)
        gslot[tid] = rowptr[tid << shift] + atomicAdd(&gcur[tid], scnt[tid]);
    __syncthreads();
#pragma unroll
    for (int u = 0; u < 16; ++u) {
        if (eb[u] >= 0) {
            int idx = atomicAdd(&scur[eb[u]], 1);
            sdata[idx] = make_int2(epk[u], __float_as_int(ew[u]));
            sbkt[idx] = (unsigned short)eb[u];
        }
    }
    __syncthreads();
    int cntR = min(4096, E - base);
    for (int i = tid; i < cntR; i += 256) {
        int b = sbkt[i];
        epack_mid[gslot[b] + (i - sofs[b])] = sdata[i];
    }
}

// ---------------- pass C: within-bucket CSR placement ----------------
__global__ __launch_bounds__(256) void bucket_sort_kernel(
        const int* __restrict__ rowptr, const int2* __restrict__ epack_mid,
        int2* __restrict__ epack, int N, int shift) {
    __shared__ int lcur[4096];
    int b = blockIdx.x;
    int tid = threadIdx.x;
    int rows = 1 << shift;
    int row0 = b << shift;
    for (int j = tid; j < rows; j += 256) {
        int rid = row0 + j;
        if (rid < N) lcur[j] = rowptr[rid];
    }
    __syncthreads();
    int slice0 = rowptr[row0];
    int slice1 = rowptr[min(row0 + rows, N)];
    for (int i = slice0 + tid; i < slice1; i += 256) {
        int2 p = epack_mid[i];
        int rl = ((unsigned)p.x) >> 20;
        int pos = atomicAdd(&lcur[rl], 1);
        epack[pos] = make_int2(p.x & 0xFFFFF, p.y);
    }
}

// ---------------- W convert + transpose (one launch) ----------------
__global__ void convert_w_all(const float* __restrict__ W1, const float* __restrict__ W2,
                              const float* __restrict__ W3, _Float16* __restrict__ Wt1,
                              _Float16* __restrict__ Wt2, _Float16* __restrict__ Wt3) {
    int g = blockIdx.x * blockDim.x + threadIdx.x;
    if (g < 16384) {
        int k = g >> 7, n = g & 127;
        Wt1[n * 128 + k] = (_Float16)W1[g];
    } else if (g < 32768) {
        int h = g - 16384; int k = h >> 7, n = h & 127;
        Wt2[n * 128 + k] = (_Float16)W2[h];
    } else if (g < 40960) {
        int h = g - 32768; int k = h >> 6, n = h & 63;
        Wt3[n * 128 + k] = (_Float16)W3[h];
    }
}

// ---------------- MFMA GEMM: A[n x 128] @ W[128 x TN] -> C[n x TN] fp16 ----------------
// 256 threads (4 waves), 128-row tile; each wave computes 2 consecutive 16-row
// m-tiles (b-fragment reused for 2 MFMAs per LDS read).
template<int TN, typename AT>
__global__ __launch_bounds__(256) void gemm_mfma(const AT* __restrict__ A,
        const _Float16* __restrict__ Wt, _Float16* __restrict__ C, int n) {
    constexpr int K = 128;
    constexpr int TM = 128;
    constexpr int LDK = K + 8;
    __shared__ _Float16 As[TM][LDK];   // 34 KB
    __shared__ _Float16 Bs[TN][LDK];   // 34 KB (TN=128) / 17 KB (TN=64)

    int tid = threadIdx.x;
    int wave = tid >> 6, lane = tid & 63;
    int q = lane >> 4, t = lane & 15;
    int rowbase = blockIdx.x * TM;

    if constexpr (std::is_same<AT, float>::value) {
        for (int i = tid; i < TM * K / 4; i += 256) {
            int r = i >> 5;
            int kc = (i & 31) * 4;
            int rr = rowbase + r;
            float4 v = make_float4(0.f, 0.f, 0.f, 0.f);
            if (rr < n) v = *(const float4*)&A[(size_t)rr * K + kc];
            As[r][kc + 0] = (_Float16)v.x;
            As[r][kc + 1] = (_Float16)v.y;
            As[r][kc + 2] = (_Float16)v.z;
            As[r][kc + 3] = (_Float16)v.w;
        }
    } else {
        for (int i = tid; i < TM * K / 8; i += 256) {
            int r = i >> 4;
            int kc = (i & 15) * 8;
            int rr = rowbase + r;
            uint4 v = make_uint4(0u, 0u, 0u, 0u);
            if (rr < n) v = *(const uint4*)&A[(size_t)rr * K + kc];
            *(uint4*)&As[r][kc] = v;
        }
    }
    for (int i = tid; i < TN * K / 8; i += 256) {
        int nr = i >> 4;
        int kc = (i & 15) * 8;
        *(uint4*)&Bs[nr][kc] = *(const uint4*)&Wt[(size_t)nr * K + kc];
    }
    __syncthreads();

    int m0 = wave * 32;
    floatx4 acc0[TN / 16], acc1[TN / 16];
#pragma unroll
    for (int nt = 0; nt < TN / 16; ++nt) {
        acc0[nt] = (floatx4){0.f, 0.f, 0.f, 0.f};
        acc1[nt] = (floatx4){0.f, 0.f, 0.f, 0.f};
    }

#pragma unroll
    for (int kk = 0; kk < K; kk += 32) {
        half8 a0 = *(const half8*)&As[m0 + t][kk + q * 8];
        half8 a1 = *(const half8*)&As[m0 + 16 + t][kk + q * 8];
#pragma unroll
        for (int nt = 0; nt < TN / 16; ++nt) {
            half8 b = *(const half8*)&Bs[nt * 16 + t][kk + q * 8];
            acc0[nt] = __builtin_amdgcn_mfma_f32_16x16x32_f16(a0, b, acc0[nt], 0, 0, 0);
            acc1[nt] = __builtin_amdgcn_mfma_f32_16x16x32_f16(a1, b, acc1[nt], 0, 0, 0);
        }
    }

#pragma unroll
    for (int nt = 0; nt < TN / 16; ++nt) {
#pragma unroll
        for (int r = 0; r < 4; ++r) {
            int rr0 = rowbase + m0 + q * 4 + r;
            if (rr0 < n) C[(size_t)rr0 * TN + nt * 16 + t] = (_Float16)acc0[nt][r];
            int rr1 = rr0 + 16;
            if (rr1 < n) C[(size_t)rr1 * TN + nt * 16 + t] = (_Float16)acc1[nt][r];
        }
    }
}

// ---------------- CSR aggregation, D=128, fp16 in / fp16 out, relu ----------------
// One node per wave; lane l holds features [2l,2l+1]; predicated 8-wide
// iterations (uniform-width tail) with epack loads pipelined one iter ahead.
__global__ __launch_bounds__(256) void agg128_kernel(const __half2* __restrict__ H,
        const int* __restrict__ rowptr, const int2* __restrict__ epack,
        const float* __restrict__ wself, const float* __restrict__ bias,
        __half2* __restrict__ out, int n) {
    int node = blockIdx.x * 4 + (threadIdx.x >> 6);
    if (node >= n) return;
    int lane = threadIdx.x & 63;
    int start = rowptr[node], end = rowptr[node + 1];
    float ws = wself[node];
    float2 hs = __half22float2(H[(size_t)node * 64 + lane]);
    float ax = ws * hs.x, ay = ws * hs.y;
    if (start < end) {
        int last = end - 1;
        int2 p[8];
#pragma unroll
        for (int j = 0; j < 8; ++j) p[j] = epack[min(start + j, last)];
        for (int e = start; e < end; e += 8) {
            int en = e + 8;
            bool more = en < end;          // wave-uniform
            int2 pn[8];
            if (more) {
#pragma unroll
                for (int j = 0; j < 8; ++j) pn[j] = epack[min(en + j, last)];
            }
            __half2 hh[8];
#pragma unroll
            for (int j = 0; j < 8; ++j) hh[j] = H[(size_t)p[j].x * 64 + lane];
#pragma unroll
            for (int j = 0; j < 8; ++j) {
                float w = (e + j < end) ? __int_as_float(p[j].y) : 0.f;
                float2 f = __half22float2(hh[j]);
                ax += w * f.x; ay += w * f.y;
            }
            if (more) {
#pragma unroll
                for (int j = 0; j < 8; ++j) p[j] = pn[j];
            }
        }
    }
    float2 b = *(const float2*)&bias[2 * lane];
    float vx = fmaxf(ax + b.x, 0.0f);
    float vy = fmaxf(ay + b.y, 0.0f);
    out[(size_t)node * 64 + lane] = __floats2half2_rn(vx, vy);
}

// ---------------- CSR aggregation, D=64, fp16 in / fp32 out, no relu ----------------
__global__ __launch_bounds__(256) void agg64_kernel(const __half* __restrict__ H,
        const int* __restrict__ rowptr, const int2* __restrict__ epack,
        const float* __restrict__ wself, const float* __restrict__ bias,
        float* __restrict__ out, int n) {
    int node = blockIdx.x * 4 + (threadIdx.x >> 6);
    if (node >= n) return;
    int lane = threadIdx.x & 63;
    int start = rowptr[node], end = rowptr[node + 1];
    float ws = wself[node];
    float acc = ws * __half2float(H[(size_t)node * 64 + lane]);
    if (start < end) {
        int last = end - 1;
        int2 p[8];
#pragma unroll
        for (int j = 0; j < 8; ++j) p[j] = epack[min(start + j, last)];
        for (int e = start; e < end; e += 8) {
            int en = e + 8;
            bool more = en < end;
            int2 pn[8];
            if (more) {
#pragma unroll
                for (int j = 0; j < 8; ++j) pn[j] = epack[min(en + j, last)];
            }
            float f[8];
#pragma unroll
            for (int j = 0; j < 8; ++j) f[j] = __half2float(H[(size_t)p[j].x * 64 + lane]);
#pragma unroll
            for (int j = 0; j < 8; ++j) {
                float w = (e + j < end) ? __int_as_float(p[j].y) : 0.f;
                acc += w * f[j];
            }
            if (more) {
#pragma unroll
                for (int j = 0; j < 8; ++j) p[j] = pn[j];
            }
        }
    }
    out[(size_t)node * 64 + lane] = acc + bias[lane];
}

// ---------------- launch ----------------
extern "C" void kernel_launch(void* const* d_in, const int* in_sizes, int n_in,
                              void* d_out, int out_size, void* d_ws, size_t ws_size,
                              hipStream_t stream) {
    const float* x  = (const float*)d_in[0];
    const int*   ei = (const int*)d_in[1];
    const float* W1 = (const float*)d_in[2];
    const float* b1 = (const float*)d_in[3];
    const float* W2 = (const float*)d_in[4];
    const float* b2 = (const float*)d_in[5];
    const float* W3 = (const float*)d_in[6];
    const float* b3 = (const float*)d_in[7];
    const float* p1 = (const float*)d_in[8];
    const float* p2 = (const float*)d_in[9];

    const int N = in_sizes[0] / 128;
    const int E = in_sizes[1] / 2;
    const int* row = ei;
    const int* col = ei + E;

    // bucket shift: smallest s with ((N-1)>>s)+1 <= 256  (N=100000 -> 9, 196 buckets)
    int shift = 0;
    while ((((N - 1) >> shift) + 1) > 256) shift++;
    const int NB = ((N - 1) >> shift) + 1;

    char* p = (char*)d_ws;
    auto alloc = [&](size_t bytes) -> void* {
        void* q = (void*)p;
        p += (bytes + 255) & ~(size_t)255;
        return q;
    };
    int*      degi      = (int*)alloc((size_t)N * 4);
    int*      gcur      = (int*)alloc(256 * 4);          // contiguous with degi for one memset
    int*      rowptr    = (int*)alloc((size_t)(N + 1) * 4);
    const int NBLK      = (N + 1023) / 1024;
    int*      blocksum  = (int*)alloc((size_t)NBLK * 4);
    int*      blockoff  = (int*)alloc((size_t)NBLK * 4);
    float4*   coeff     = (float4*)alloc((size_t)N * 16);
    float*    wself     = (float*)alloc((size_t)N * 4);
    int2*     epack_mid = (int2*)alloc((size_t)E * 8);
    int2*     epack     = (int2*)alloc((size_t)E * 8);
    _Float16* Wt1       = (_Float16*)alloc(128 * 128 * 2);
    _Float16* Wt2       = (_Float16*)alloc(128 * 128 * 2);
    _Float16* Wt3       = (_Float16*)alloc(128 * 64 * 2);
    _Float16* bufH      = (_Float16*)alloc((size_t)N * 128 * 2);
    _Float16* actH      = (_Float16*)alloc((size_t)N * 128 * 2);
    (void)ws_size; (void)n_in;

    size_t zero_bytes = (size_t)((char*)rowptr - (char*)degi);
    hipMemsetAsync(degi, 0, zero_bytes, stream);

    convert_w_all<<<160, 256, 0, stream>>>(W1, W2, W3, Wt1, Wt2, Wt3);

    deg_count_kernel<<<(E + 255) / 256, 256, 0, stream>>>(row, degi, E);
    scan_block_kernel<<<NBLK, 256, 0, stream>>>(degi, rowptr, blocksum, p1, p2, coeff, wself, N);
    scan_tops_kernel<<<1, 128, 0, stream>>>(blocksum, blockoff, NBLK);
    scan_add_kernel<<<(N + 255) / 256, 256, 0, stream>>>(rowptr, blockoff, N);
    partition_kernel<<<(E + 4095) / 4096, 256, 0, stream>>>(row, col, rowptr, gcur, coeff,
                                                            epack_mid, E, shift, NB);
    bucket_sort_kernel<<<NB, 256, 0, stream>>>(rowptr, epack_mid, epack, N, shift);

    float* out = (float*)d_out;
    int aggGrid = (N + 3) / 4;
    int gemmGrid = (N + 127) / 128;
    // layer 1
    gemm_mfma<128, float><<<gemmGrid, 256, 0, stream>>>(x, Wt1, bufH, N);
    agg128_kernel<<<aggGrid, 256, 0, stream>>>((const __half2*)bufH, rowptr, epack, wself,
                                               b1, (__half2*)actH, N);
    // layer 2
    gemm_mfma<128, _Float16><<<gemmGrid, 256, 0, stream>>>(actH, Wt2, bufH, N);
    agg128_kernel<<<aggGrid, 256, 0, stream>>>((const __half2*)bufH, rowptr, epack, wself,
                                               b2, (__half2*)actH, N);
    // layer 3 (D_OUT=64, no relu)
    gemm_mfma<64, _Float16><<<gemmGrid, 256, 0, stream>>>(actH, Wt3, bufH, N);
    agg64_kernel<<<aggGrid, 256, 0, stream>>>((const __half*)bufH, rowptr, epack, wself,
                                              b3, out, N);
}

// Round 8
// 487.189 us; speedup vs baseline: 1.9603x; 1.0984x over previous
//
#include <hip/hip_runtime.h>
#include <hip/hip_fp16.h>
#include <math.h>
#include <type_traits>

typedef _Float16 half8 __attribute__((ext_vector_type(8)));
typedef float floatx4 __attribute__((ext_vector_type(4)));

// ---------------- fused: degree count + W convert/transpose ----------------
__global__ void deg_convert_kernel(const int* __restrict__ row, int* __restrict__ degi, int E,
                                   const float* __restrict__ W1, const float* __restrict__ W2,
                                   const float* __restrict__ W3, _Float16* __restrict__ Wt1,
                                   _Float16* __restrict__ Wt2, _Float16* __restrict__ Wt3,
                                   int degBlocks) {
    if ((int)blockIdx.x < degBlocks) {
        int g = blockIdx.x * 256 + threadIdx.x;
        if (g < E) atomicAdd(&degi[row[g]], 1);
    } else {
        int g = (blockIdx.x - degBlocks) * 256 + threadIdx.x;
        if (g < 16384) {
            int k = g >> 7, n = g & 127;
            Wt1[n * 128 + k] = (_Float16)W1[g];
        } else if (g < 32768) {
            int h = g - 16384; int k = h >> 7, n = h & 127;
            Wt2[n * 128 + k] = (_Float16)W2[h];
        } else if (g < 40960) {
            int h = g - 32768; int k = h >> 6, n = h & 63;
            Wt3[n * 128 + k] = (_Float16)W3[h];
        }
    }
}

// ---------------- per-node GSO coefficient helper ----------------
__device__ __forceinline__ float pow_z(float d, float e) {
    float p = powf(d, e);
    return isinf(p) ? 0.0f : p;   // reference zeroes inf from 0**negative
}

__device__ __forceinline__ void gso_coeff(float deg, const float* __restrict__ p1,
                                          const float* __restrict__ p2,
                                          float4* cf, float* ws) {
    float m1a = p1[0], m2a = p1[1], m3a = p1[2], e1a = p1[3], e2a = p1[4], e3a = p1[5], aa = p1[6];
    float m1b = p2[0], m2b = p2[1], m3b = p2[2], e1b = p2[3], e2b = p2[4], e3b = p2[5], ab = p2[6];
    float d1 = deg + aa, d2 = deg + ab;
    float pa1 = pow_z(d1, e1a), pa2 = pow_z(d1, e2a), pa3 = pow_z(d1, e3a);
    float pb1 = pow_z(d2, e1b), pb2 = pow_z(d2, e2b), pb3 = pow_z(d2, e3b);
    *cf = make_float4(m2a * pa2, pa3, m2b * pb2, pb3);
    *ws = m1a * pa1 + m2a * pa2 * pa3 + m3a
        + m1b * pb1 + m2b * pb2 * pb3 + m3b;
}

// ---------------- fused: block scan of degrees + GSO coefficients ----------------
__global__ void scan_block_kernel(const int* __restrict__ degi, int* __restrict__ rowptr,
                                  int* __restrict__ blocksum,
                                  const float* __restrict__ p1, const float* __restrict__ p2,
                                  float4* __restrict__ coeff, float* __restrict__ wself, int n) {
    __shared__ int sums[256];
    int tid = threadIdx.x;
    int base = blockIdx.x * 1024 + tid * 4;
    int d0 = (base + 0 < n) ? degi[base + 0] : 0;
    int d1 = (base + 1 < n) ? degi[base + 1] : 0;
    int d2 = (base + 2 < n) ? degi[base + 2] : 0;
    int d3 = (base + 3 < n) ? degi[base + 3] : 0;
    int s0 = d0, s1 = s0 + d1, s2 = s1 + d2, s3 = s2 + d3;
    sums[tid] = s3;
    __syncthreads();
    for (int off = 1; off < 256; off <<= 1) {
        int v = (tid >= off) ? sums[tid - off] : 0;
        __syncthreads();
        sums[tid] += v;
        __syncthreads();
    }
    int excl = sums[tid] - s3;
    if (base + 0 < n) rowptr[base + 1] = excl + s0;
    if (base + 1 < n) rowptr[base + 2] = excl + s1;
    if (base + 2 < n) rowptr[base + 3] = excl + s2;
    if (base + 3 < n) rowptr[base + 4] = excl + s3;
    if (tid == 255) blocksum[blockIdx.x] = sums[255];
    int dd[4] = {d0, d1, d2, d3};
#pragma unroll
    for (int u = 0; u < 4; ++u) {
        if (base + u < n) {
            float4 cf; float ws;
            gso_coeff((float)dd[u], p1, p2, &cf, &ws);
            coeff[base + u] = cf;
            wself[base + u] = ws;
        }
    }
}

// ---------------- scan_add with inline top-scan (each block re-scans blocksum) ----
__global__ void scan_add_kernel(int* __restrict__ rowptr, const int* __restrict__ blocksum,
                                int n, int nblk) {
    __shared__ int s[128];
    int tid = threadIdx.x;
    if (tid < 128) s[tid] = (tid < nblk) ? blocksum[tid] : 0;
    __syncthreads();
    for (int off = 1; off < 128; off <<= 1) {
        int v = 0;
        if (tid < 128 && tid >= off) v = s[tid - off];
        __syncthreads();
        if (tid < 128) s[tid] += v;
        __syncthreads();
    }
    int g = blockIdx.x * 256 + tid;
    if (g == 0) rowptr[0] = 0;
    if (g < n) {
        int b = g >> 10;
        int off = (b == 0) ? 0 : s[b - 1];
        rowptr[g + 1] += off;
    }
}

// ---------------- pass B: radix partition edges by row-bucket ----------------
__global__ __launch_bounds__(256) void partition_kernel(
        const int* __restrict__ row, const int* __restrict__ col,
        const int* __restrict__ rowptr, int* __restrict__ gcur,
        const float4* __restrict__ coeff, int2* __restrict__ epack_mid,
        int E, int shift, int NB) {
    __shared__ int scnt[256], sofs[256], scur[256], gslot[256];
    __shared__ int2 sdata[4096];
    __shared__ unsigned short sbkt[4096];

    int tid = threadIdx.x;
    int base = blockIdx.x * 4096;
    scnt[tid] = 0;
    __syncthreads();

    int epk[16]; float ew[16]; int eb[16];
#pragma unroll
    for (int u = 0; u < 16; ++u) {
        int e = base + u * 256 + tid;
        eb[u] = -1;
        if (e < E) {
            int r = row[e], c = col[e];
            int b = r >> shift;
            eb[u] = b;
            atomicAdd(&scnt[b], 1);
            float4 cr = coeff[r], cc = coeff[c];
            ew[u] = cr.x * cc.y + cr.z * cc.w;
            epk[u] = c | ((r & ((1 << shift) - 1)) << 20);
        }
    }
    __syncthreads();
    sofs[tid] = scnt[tid];
    __syncthreads();
    for (int off = 1; off < 256; off <<= 1) {
        int v = (tid >= off) ? sofs[tid - off] : 0;
        __syncthreads();
        sofs[tid] += v;
        __syncthreads();
    }
    int excl = sofs[tid] - scnt[tid];
    sofs[tid] = excl;
    scur[tid] = excl;
    if (tid < NB && scnt[tid] > 0)
        gslot[tid] = rowptr[tid << shift] + atomicAdd(&gcur[tid], scnt[tid]);
    __syncthreads();
#pragma unroll
    for (int u = 0; u < 16; ++u) {
        if (eb[u] >= 0) {
            int idx = atomicAdd(&scur[eb[u]], 1);
            sdata[idx] = make_int2(epk[u], __float_as_int(ew[u]));
            sbkt[idx] = (unsigned short)eb[u];
        }
    }
    __syncthreads();
    int cntR = min(4096, E - base);
    for (int i = tid; i < cntR; i += 256) {
        int b = sbkt[i];
        epack_mid[gslot[b] + (i - sofs[b])] = sdata[i];
    }
}

// ---------------- pass C: within-bucket CSR placement ----------------
__global__ __launch_bounds__(256) void bucket_sort_kernel(
        const int* __restrict__ rowptr, const int2* __restrict__ epack_mid,
        int2* __restrict__ epack, int N, int shift) {
    __shared__ int lcur[4096];
    int b = blockIdx.x;
    int tid = threadIdx.x;
    int rows = 1 << shift;
    int row0 = b << shift;
    for (int j = tid; j < rows; j += 256) {
        int rid = row0 + j;
        if (rid < N) lcur[j] = rowptr[rid];
    }
    __syncthreads();
    int slice0 = rowptr[row0];
    int slice1 = rowptr[min(row0 + rows, N)];
    for (int i = slice0 + tid; i < slice1; i += 256) {
        int2 p = epack_mid[i];
        int rl = ((unsigned)p.x) >> 20;
        int pos = atomicAdd(&lcur[rl], 1);
        epack[pos] = make_int2(p.x & 0xFFFFF, p.y);
    }
}

// ---------------- MFMA GEMM: A[n x 128] @ W[128 x TN] -> C[n x TN] fp16 ----------------
template<int TN, typename AT>
__global__ __launch_bounds__(256) void gemm_mfma(const AT* __restrict__ A,
        const _Float16* __restrict__ Wt, _Float16* __restrict__ C, int n) {
    constexpr int K = 128;
    constexpr int TM = 128;
    constexpr int LDK = K + 8;
    __shared__ _Float16 As[TM][LDK];
    __shared__ _Float16 Bs[TN][LDK];

    int tid = threadIdx.x;
    int wave = tid >> 6, lane = tid & 63;
    int q = lane >> 4, t = lane & 15;
    int rowbase = blockIdx.x * TM;

    if constexpr (std::is_same<AT, float>::value) {
        for (int i = tid; i < TM * K / 4; i += 256) {
            int r = i >> 5;
            int kc = (i & 31) * 4;
            int rr = rowbase + r;
            float4 v = make_float4(0.f, 0.f, 0.f, 0.f);
            if (rr < n) v = *(const float4*)&A[(size_t)rr * K + kc];
            As[r][kc + 0] = (_Float16)v.x;
            As[r][kc + 1] = (_Float16)v.y;
            As[r][kc + 2] = (_Float16)v.z;
            As[r][kc + 3] = (_Float16)v.w;
        }
    } else {
        for (int i = tid; i < TM * K / 8; i += 256) {
            int r = i >> 4;
            int kc = (i & 15) * 8;
            int rr = rowbase + r;
            uint4 v = make_uint4(0u, 0u, 0u, 0u);
            if (rr < n) v = *(const uint4*)&A[(size_t)rr * K + kc];
            *(uint4*)&As[r][kc] = v;
        }
    }
    for (int i = tid; i < TN * K / 8; i += 256) {
        int nr = i >> 4;
        int kc = (i & 15) * 8;
        *(uint4*)&Bs[nr][kc] = *(const uint4*)&Wt[(size_t)nr * K + kc];
    }
    __syncthreads();

    int m0 = wave * 32;
    floatx4 acc0[TN / 16], acc1[TN / 16];
#pragma unroll
    for (int nt = 0; nt < TN / 16; ++nt) {
        acc0[nt] = (floatx4){0.f, 0.f, 0.f, 0.f};
        acc1[nt] = (floatx4){0.f, 0.f, 0.f, 0.f};
    }

#pragma unroll
    for (int kk = 0; kk < K; kk += 32) {
        half8 a0 = *(const half8*)&As[m0 + t][kk + q * 8];
        half8 a1 = *(const half8*)&As[m0 + 16 + t][kk + q * 8];
#pragma unroll
        for (int nt = 0; nt < TN / 16; ++nt) {
            half8 b = *(const half8*)&Bs[nt * 16 + t][kk + q * 8];
            acc0[nt] = __builtin_amdgcn_mfma_f32_16x16x32_f16(a0, b, acc0[nt], 0, 0, 0);
            acc1[nt] = __builtin_amdgcn_mfma_f32_16x16x32_f16(a1, b, acc1[nt], 0, 0, 0);
        }
    }

#pragma unroll
    for (int nt = 0; nt < TN / 16; ++nt) {
#pragma unroll
        for (int r = 0; r < 4; ++r) {
            int rr0 = rowbase + m0 + q * 4 + r;
            if (rr0 < n) C[(size_t)rr0 * TN + nt * 16 + t] = (_Float16)acc0[nt][r];
            int rr1 = rr0 + 16;
            if (rr1 < n) C[(size_t)rr1 * TN + nt * 16 + t] = (_Float16)acc1[nt][r];
        }
    }
}

// ---------------- CSR aggregation, D=128, fp16 in / fp16 out, relu ----------------
// One node per wave; lane l holds features [2l,2l+1]. Unpredicated 16/8/4/1
// cascade: avg-degree-16 nodes do one 16-wide gather burst; tail <= 1x8 + 1x4
// + <=3 singles (was: avg ~4 serialized singles with plain 8+1).
__global__ __launch_bounds__(256) void agg128_kernel(const __half2* __restrict__ H,
        const int* __restrict__ rowptr, const int2* __restrict__ epack,
        const float* __restrict__ wself, const float* __restrict__ bias,
        __half2* __restrict__ out, int n) {
    int node = blockIdx.x * 4 + (threadIdx.x >> 6);
    if (node >= n) return;
    int lane = threadIdx.x & 63;
    int start = rowptr[node], end = rowptr[node + 1];
    float ws = wself[node];
    float2 hs = __half22float2(H[(size_t)node * 64 + lane]);
    float ax = ws * hs.x, ay = ws * hs.y;
    int e = start;
    for (; e + 16 <= end; e += 16) {
        int2 p[16];
#pragma unroll
        for (int j = 0; j < 16; ++j) p[j] = epack[e + j];
        __half2 hh[16];
#pragma unroll
        for (int j = 0; j < 16; ++j) hh[j] = H[(size_t)p[j].x * 64 + lane];
#pragma unroll
        for (int j = 0; j < 16; ++j) {
            float w = __int_as_float(p[j].y);
            float2 f = __half22float2(hh[j]);
            ax += w * f.x; ay += w * f.y;
        }
    }
    if (e + 8 <= end) {
        int2 p[8];
#pragma unroll
        for (int j = 0; j < 8; ++j) p[j] = epack[e + j];
        __half2 hh[8];
#pragma unroll
        for (int j = 0; j < 8; ++j) hh[j] = H[(size_t)p[j].x * 64 + lane];
#pragma unroll
        for (int j = 0; j < 8; ++j) {
            float w = __int_as_float(p[j].y);
            float2 f = __half22float2(hh[j]);
            ax += w * f.x; ay += w * f.y;
        }
        e += 8;
    }
    if (e + 4 <= end) {
        int2 p[4];
#pragma unroll
        for (int j = 0; j < 4; ++j) p[j] = epack[e + j];
        __half2 hh[4];
#pragma unroll
        for (int j = 0; j < 4; ++j) hh[j] = H[(size_t)p[j].x * 64 + lane];
#pragma unroll
        for (int j = 0; j < 4; ++j) {
            float w = __int_as_float(p[j].y);
            float2 f = __half22float2(hh[j]);
            ax += w * f.x; ay += w * f.y;
        }
        e += 4;
    }
    for (; e < end; ++e) {
        int2 pe = epack[e];
        float w = __int_as_float(pe.y);
        float2 f = __half22float2(H[(size_t)pe.x * 64 + lane]);
        ax += w * f.x; ay += w * f.y;
    }
    float2 b = *(const float2*)&bias[2 * lane];
    float vx = fmaxf(ax + b.x, 0.0f);
    float vy = fmaxf(ay + b.y, 0.0f);
    out[(size_t)node * 64 + lane] = __floats2half2_rn(vx, vy);
}

// ---------------- CSR aggregation, D=64, fp16 in / fp32 out, no relu ----------------
__global__ __launch_bounds__(256) void agg64_kernel(const __half* __restrict__ H,
        const int* __restrict__ rowptr, const int2* __restrict__ epack,
        const float* __restrict__ wself, const float* __restrict__ bias,
        float* __restrict__ out, int n) {
    int node = blockIdx.x * 4 + (threadIdx.x >> 6);
    if (node >= n) return;
    int lane = threadIdx.x & 63;
    int start = rowptr[node], end = rowptr[node + 1];
    float ws = wself[node];
    float acc = ws * __half2float(H[(size_t)node * 64 + lane]);
    int e = start;
    for (; e + 16 <= end; e += 16) {
        int2 p[16];
#pragma unroll
        for (int j = 0; j < 16; ++j) p[j] = epack[e + j];
        float f[16];
#pragma unroll
        for (int j = 0; j < 16; ++j) f[j] = __half2float(H[(size_t)p[j].x * 64 + lane]);
#pragma unroll
        for (int j = 0; j < 16; ++j) acc += __int_as_float(p[j].y) * f[j];
    }
    if (e + 8 <= end) {
        int2 p[8];
#pragma unroll
        for (int j = 0; j < 8; ++j) p[j] = epack[e + j];
        float f[8];
#pragma unroll
        for (int j = 0; j < 8; ++j) f[j] = __half2float(H[(size_t)p[j].x * 64 + lane]);
#pragma unroll
        for (int j = 0; j < 8; ++j) acc += __int_as_float(p[j].y) * f[j];
        e += 8;
    }
    if (e + 4 <= end) {
        int2 p[4];
#pragma unroll
        for (int j = 0; j < 4; ++j) p[j] = epack[e + j];
        float f[4];
#pragma unroll
        for (int j = 0; j < 4; ++j) f[j] = __half2float(H[(size_t)p[j].x * 64 + lane]);
#pragma unroll
        for (int j = 0; j < 4; ++j) acc += __int_as_float(p[j].y) * f[j];
        e += 4;
    }
    for (; e < end; ++e) {
        int2 pe = epack[e];
        acc += __int_as_float(pe.y) * __half2float(H[(size_t)pe.x * 64 + lane]);
    }
    out[(size_t)node * 64 + lane] = acc + bias[lane];
}

// ---------------- launch ----------------
extern "C" void kernel_launch(void* const* d_in, const int* in_sizes, int n_in,
                              void* d_out, int out_size, void* d_ws, size_t ws_size,
                              hipStream_t stream) {
    const float* x  = (const float*)d_in[0];
    const int*   ei = (const int*)d_in[1];
    const float* W1 = (const float*)d_in[2];
    const float* b1 = (const float*)d_in[3];
    const float* W2 = (const float*)d_in[4];
    const float* b2 = (const float*)d_in[5];
    const float* W3 = (const float*)d_in[6];
    const float* b3 = (const float*)d_in[7];
    const float* p1 = (const float*)d_in[8];
    const float* p2 = (const float*)d_in[9];

    const int N = in_sizes[0] / 128;
    const int E = in_sizes[1] / 2;
    const int* row = ei;
    const int* col = ei + E;

    // bucket shift: smallest s with ((N-1)>>s)+1 <= 256  (N=100000 -> 9, 196 buckets)
    int shift = 0;
    while ((((N - 1) >> shift) + 1) > 256) shift++;
    const int NB = ((N - 1) >> shift) + 1;

    char* p = (char*)d_ws;
    auto alloc = [&](size_t bytes) -> void* {
        void* q = (void*)p;
        p += (bytes + 255) & ~(size_t)255;
        return q;
    };
    int*      degi      = (int*)alloc((size_t)N * 4);
    int*      gcur      = (int*)alloc(256 * 4);          // contiguous with degi for one memset
    int*      rowptr    = (int*)alloc((size_t)(N + 1) * 4);
    const int NBLK      = (N + 1023) / 1024;             // 98 (<=128 for scan_add inline top)
    int*      blocksum  = (int*)alloc((size_t)NBLK * 4);
    float4*   coeff     = (float4*)alloc((size_t)N * 16);
    float*    wself     = (float*)alloc((size_t)N * 4);
    int2*     epack_mid = (int2*)alloc((size_t)E * 8);
    int2*     epack     = (int2*)alloc((size_t)E * 8);
    _Float16* Wt1       = (_Float16*)alloc(128 * 128 * 2);
    _Float16* Wt2       = (_Float16*)alloc(128 * 128 * 2);
    _Float16* Wt3       = (_Float16*)alloc(128 * 64 * 2);
    _Float16* bufH      = (_Float16*)alloc((size_t)N * 128 * 2);
    _Float16* actH      = (_Float16*)alloc((size_t)N * 128 * 2);
    (void)ws_size; (void)n_in;

    size_t zero_bytes = (size_t)((char*)rowptr - (char*)degi);
    hipMemsetAsync(degi, 0, zero_bytes, stream);

    const int degBlocks = (E + 255) / 256;
    deg_convert_kernel<<<degBlocks + 160, 256, 0, stream>>>(row, degi, E, W1, W2, W3,
                                                            Wt1, Wt2, Wt3, degBlocks);
    scan_block_kernel<<<NBLK, 256, 0, stream>>>(degi, rowptr, blocksum, p1, p2, coeff, wself, N);
    scan_add_kernel<<<(N + 255) / 256, 256, 0, stream>>>(rowptr, blocksum, N, NBLK);
    partition_kernel<<<(E + 4095) / 4096, 256, 0, stream>>>(row, col, rowptr, gcur, coeff,
                                                            epack_mid, E, shift, NB);
    bucket_sort_kernel<<<NB, 256, 0, stream>>>(rowptr, epack_mid, epack, N, shift);

    float* out = (float*)d_out;
    int aggGrid = (N + 3) / 4;
    int gemmGrid = (N + 127) / 128;
    // layer 1
    gemm_mfma<128, float><<<gemmGrid, 256, 0, stream>>>(x, Wt1, bufH, N);
    agg128_kernel<<<aggGrid, 256, 0, stream>>>((const __half2*)bufH, rowptr, epack, wself,
                                               b1, (__half2*)actH, N);
    // layer 2
    gemm_mfma<128, _Float16><<<gemmGrid, 256, 0, stream>>>(actH, Wt2, bufH, N);
    agg128_kernel<<<aggGrid, 256, 0, stream>>>((const __half2*)bufH, rowptr, epack, wself,
                                               b2, (__half2*)actH, N);
    // layer 3 (D_OUT=64, no relu)
    gemm_mfma<64, _Float16><<<gemmGrid, 256, 0, stream>>>(actH, Wt3, bufH, N);
    agg64_kernel<<<aggGrid, 256, 0, stream>>>((const __half*)bufH, rowptr, epack, wself,
                                              b3, out, N);
}

// Round 9
// 485.788 us; speedup vs baseline: 1.9660x; 1.0029x over previous
//
#include <hip/hip_runtime.h>
#include <hip/hip_fp16.h>
#include <math.h>
#include <type_traits>

typedef _Float16 half8 __attribute__((ext_vector_type(8)));
typedef float floatx4 __attribute__((ext_vector_type(4)));

// ---------------- shared GEMM body: A[n x 128] @ W[128 x TN] -> C fp16 ----------------
// TM=128 rows/block, full K=128 in LDS, 2 m-tiles per wave.
// WFP32: stage B from row-major fp32 W[k][n] via LDS transpose (no pre-convert needed).
template<int TN, typename AT, bool WFP32>
__device__ __forceinline__ void gemm_body(const AT* __restrict__ A,
        const void* __restrict__ Wsrc, _Float16* __restrict__ C, int n, int blk,
        _Float16* lds) {
    constexpr int K = 128;
    constexpr int TM = 128;
    constexpr int LDK = K + 8;
    _Float16 (*As)[LDK] = (_Float16 (*)[LDK])lds;
    _Float16 (*Bs)[LDK] = (_Float16 (*)[LDK])(lds + TM * LDK);

    int tid = threadIdx.x;
    int wave = tid >> 6, lane = tid & 63;
    int q = lane >> 4, t = lane & 15;
    int rowbase = blk * TM;

    if constexpr (std::is_same<AT, float>::value) {
        for (int i = tid; i < TM * K / 4; i += 256) {
            int r = i >> 5;
            int kc = (i & 31) * 4;
            int rr = rowbase + r;
            float4 v = make_float4(0.f, 0.f, 0.f, 0.f);
            if (rr < n) v = *(const float4*)&A[(size_t)rr * K + kc];
            As[r][kc + 0] = (_Float16)v.x;
            As[r][kc + 1] = (_Float16)v.y;
            As[r][kc + 2] = (_Float16)v.z;
            As[r][kc + 3] = (_Float16)v.w;
        }
    } else {
        for (int i = tid; i < TM * K / 8; i += 256) {
            int r = i >> 4;
            int kc = (i & 15) * 8;
            int rr = rowbase + r;
            uint4 v = make_uint4(0u, 0u, 0u, 0u);
            if (rr < n) v = *(const uint4*)&A[(size_t)rr * K + kc];
            *(uint4*)&As[r][kc] = v;
        }
    }
    if constexpr (WFP32) {
        const float* W = (const float*)Wsrc;       // [K][TN] row-major fp32
        for (int i = tid; i < K * TN / 4; i += 256) {
            float4 v = *(const float4*)&W[i * 4];
            int k = (i * 4) / TN, nn = (i * 4) % TN;
            Bs[nn + 0][k] = (_Float16)v.x;
            Bs[nn + 1][k] = (_Float16)v.y;
            Bs[nn + 2][k] = (_Float16)v.z;
            Bs[nn + 3][k] = (_Float16)v.w;
        }
    } else {
        const _Float16* Wt = (const _Float16*)Wsrc;  // [TN][K] pre-transposed fp16
        for (int i = tid; i < TN * K / 8; i += 256) {
            int nr = i >> 4;
            int kc = (i & 15) * 8;
            *(uint4*)&Bs[nr][kc] = *(const uint4*)&Wt[(size_t)nr * K + kc];
        }
    }
    __syncthreads();

    int m0 = wave * 32;
    floatx4 acc0[TN / 16], acc1[TN / 16];
#pragma unroll
    for (int nt = 0; nt < TN / 16; ++nt) {
        acc0[nt] = (floatx4){0.f, 0.f, 0.f, 0.f};
        acc1[nt] = (floatx4){0.f, 0.f, 0.f, 0.f};
    }

#pragma unroll
    for (int kk = 0; kk < K; kk += 32) {
        half8 a0 = *(const half8*)&As[m0 + t][kk + q * 8];
        half8 a1 = *(const half8*)&As[m0 + 16 + t][kk + q * 8];
#pragma unroll
        for (int nt = 0; nt < TN / 16; ++nt) {
            half8 b = *(const half8*)&Bs[nt * 16 + t][kk + q * 8];
            acc0[nt] = __builtin_amdgcn_mfma_f32_16x16x32_f16(a0, b, acc0[nt], 0, 0, 0);
            acc1[nt] = __builtin_amdgcn_mfma_f32_16x16x32_f16(a1, b, acc1[nt], 0, 0, 0);
        }
    }

#pragma unroll
    for (int nt = 0; nt < TN / 16; ++nt) {
#pragma unroll
        for (int r = 0; r < 4; ++r) {
            int rr0 = rowbase + m0 + q * 4 + r;
            if (rr0 < n) C[(size_t)rr0 * TN + nt * 16 + t] = (_Float16)acc0[nt][r];
            int rr1 = rr0 + 16;
            if (rr1 < n) C[(size_t)rr1 * TN + nt * 16 + t] = (_Float16)acc1[nt][r];
        }
    }
}

// ---------------- fused K1: gemm1 (x@W1) + degree count + W2/W3 convert ----------------
// gemm blocks first (long-running, start early), deg blocks overlap (atomic-bound,
// disjoint pipes), conv blocks trail. gemm1 stages W1 fp32 directly -> no Wt1, no race.
__global__ __launch_bounds__(256) void setup_fused_kernel(
        const float* __restrict__ x, const float* __restrict__ W1,
        _Float16* __restrict__ bufH, int N,
        const int* __restrict__ row, int* __restrict__ degi, int E,
        const float* __restrict__ W2, const float* __restrict__ W3,
        _Float16* __restrict__ Wt2, _Float16* __restrict__ Wt3,
        int gemmBlocks, int degBlocks4) {
    __shared__ _Float16 lds[(128 + 128) * 136];
    int b = blockIdx.x;
    if (b < gemmBlocks) {
        gemm_body<128, float, true>(x, W1, bufH, N, b, lds);
    } else if (b < gemmBlocks + degBlocks4) {
        int e0 = (b - gemmBlocks) * 1024 + threadIdx.x * 4;
        if (e0 + 3 < E) {
            int4 r4 = *(const int4*)&row[e0];
            atomicAdd(&degi[r4.x], 1);
            atomicAdd(&degi[r4.y], 1);
            atomicAdd(&degi[r4.z], 1);
            atomicAdd(&degi[r4.w], 1);
        } else {
#pragma unroll
            for (int j = 0; j < 4; ++j)
                if (e0 + j < E) atomicAdd(&degi[row[e0 + j]], 1);
        }
    } else {
        int g = (b - gemmBlocks - degBlocks4) * 256 + threadIdx.x;
        if (g < 16384) {
            int k = g >> 7, n = g & 127;
            Wt2[n * 128 + k] = (_Float16)W2[g];
        } else if (g < 24576) {
            int h = g - 16384; int k = h >> 6, n = h & 63;
            Wt3[n * 128 + k] = (_Float16)W3[h];
        }
    }
}

// ---------------- standalone GEMM (layers 2, 3) ----------------
template<int TN>
__global__ __launch_bounds__(256) void gemm_mfma(const _Float16* __restrict__ A,
        const _Float16* __restrict__ Wt, _Float16* __restrict__ C, int n) {
    __shared__ _Float16 lds[(128 + TN) * 136];
    gemm_body<TN, _Float16, false>(A, Wt, C, n, blockIdx.x, lds);
}

// ---------------- per-node GSO coefficient helper ----------------
__device__ __forceinline__ float pow_z(float d, float e) {
    float p = powf(d, e);
    return isinf(p) ? 0.0f : p;   // reference zeroes inf from 0**negative
}

__device__ __forceinline__ void gso_coeff(float deg, const float* __restrict__ p1,
                                          const float* __restrict__ p2,
                                          float4* cf, float* ws) {
    float m1a = p1[0], m2a = p1[1], m3a = p1[2], e1a = p1[3], e2a = p1[4], e3a = p1[5], aa = p1[6];
    float m1b = p2[0], m2b = p2[1], m3b = p2[2], e1b = p2[3], e2b = p2[4], e3b = p2[5], ab = p2[6];
    float d1 = deg + aa, d2 = deg + ab;
    float pa1 = pow_z(d1, e1a), pa2 = pow_z(d1, e2a), pa3 = pow_z(d1, e3a);
    float pb1 = pow_z(d2, e1b), pb2 = pow_z(d2, e2b), pb3 = pow_z(d2, e3b);
    *cf = make_float4(m2a * pa2, pa3, m2b * pb2, pb3);
    *ws = m1a * pa1 + m2a * pa2 * pa3 + m3a
        + m1b * pb1 + m2b * pb2 * pb3 + m3b;
}

// ---------------- fused: block scan of degrees + GSO coefficients ----------------
__global__ void scan_block_kernel(const int* __restrict__ degi, int* __restrict__ rowptr,
                                  int* __restrict__ blocksum,
                                  const float* __restrict__ p1, const float* __restrict__ p2,
                                  float4* __restrict__ coeff, float* __restrict__ wself, int n) {
    __shared__ int sums[256];
    int tid = threadIdx.x;
    int base = blockIdx.x * 1024 + tid * 4;
    int d0 = (base + 0 < n) ? degi[base + 0] : 0;
    int d1 = (base + 1 < n) ? degi[base + 1] : 0;
    int d2 = (base + 2 < n) ? degi[base + 2] : 0;
    int d3 = (base + 3 < n) ? degi[base + 3] : 0;
    int s0 = d0, s1 = s0 + d1, s2 = s1 + d2, s3 = s2 + d3;
    sums[tid] = s3;
    __syncthreads();
    for (int off = 1; off < 256; off <<= 1) {
        int v = (tid >= off) ? sums[tid - off] : 0;
        __syncthreads();
        sums[tid] += v;
        __syncthreads();
    }
    int excl = sums[tid] - s3;
    if (base + 0 < n) rowptr[base + 1] = excl + s0;
    if (base + 1 < n) rowptr[base + 2] = excl + s1;
    if (base + 2 < n) rowptr[base + 3] = excl + s2;
    if (base + 3 < n) rowptr[base + 4] = excl + s3;
    if (tid == 255) blocksum[blockIdx.x] = sums[255];
    int dd[4] = {d0, d1, d2, d3};
#pragma unroll
    for (int u = 0; u < 4; ++u) {
        if (base + u < n) {
            float4 cf; float ws;
            gso_coeff((float)dd[u], p1, p2, &cf, &ws);
            coeff[base + u] = cf;
            wself[base + u] = ws;
        }
    }
}

// ---------------- scan_add with inline top-scan ----------------
__global__ void scan_add_kernel(int* __restrict__ rowptr, const int* __restrict__ blocksum,
                                int n, int nblk) {
    __shared__ int s[128];
    int tid = threadIdx.x;
    if (tid < 128) s[tid] = (tid < nblk) ? blocksum[tid] : 0;
    __syncthreads();
    for (int off = 1; off < 128; off <<= 1) {
        int v = 0;
        if (tid < 128 && tid >= off) v = s[tid - off];
        __syncthreads();
        if (tid < 128) s[tid] += v;
        __syncthreads();
    }
    int g = blockIdx.x * 256 + tid;
    if (g == 0) rowptr[0] = 0;
    if (g < n) {
        int b = g >> 10;
        int off = (b == 0) ? 0 : s[b - 1];
        rowptr[g + 1] += off;
    }
}

// ---------------- pass B: radix partition, single-phase LDS counting ----------------
__global__ __launch_bounds__(256) void partition_kernel(
        const int* __restrict__ row, const int* __restrict__ col,
        const int* __restrict__ rowptr, int* __restrict__ gcur,
        const float4* __restrict__ coeff, int2* __restrict__ epack_mid,
        int E, int shift, int NB) {
    __shared__ int scnt[256], sofs[256], gslot[256];
    __shared__ int2 sdata[4096];
    __shared__ unsigned short sbkt[4096];

    int tid = threadIdx.x;
    int base = blockIdx.x * 4096;
    scnt[tid] = 0;
    __syncthreads();

    int epk[16]; float ew[16]; int eb[16]; int eidx[16];
#pragma unroll
    for (int v = 0; v < 4; ++v) {
        int e0 = base + v * 1024 + tid * 4;
        int4 r4, c4;
        bool full = (e0 + 3 < E);
        if (full) {
            r4 = *(const int4*)&row[e0];
            c4 = *(const int4*)&col[e0];
        }
#pragma unroll
        for (int j = 0; j < 4; ++j) {
            int u = v * 4 + j;
            eb[u] = -1;
            int r, c;
            if (full) {
                r = (&r4.x)[j]; c = (&c4.x)[j];
            } else {
                if (e0 + j >= E) continue;
                r = row[e0 + j]; c = col[e0 + j];
            }
            int b = r >> shift;
            eb[u] = b;
            eidx[u] = atomicAdd(&scnt[b], 1);     // single-phase: keep the index
            float4 cr = coeff[r], cc = coeff[c];
            ew[u] = cr.x * cc.y + cr.z * cc.w;
            epk[u] = c | ((r & ((1 << shift) - 1)) << 20);
        }
    }
    __syncthreads();
    sofs[tid] = scnt[tid];
    __syncthreads();
    for (int off = 1; off < 256; off <<= 1) {
        int v = (tid >= off) ? sofs[tid - off] : 0;
        __syncthreads();
        sofs[tid] += v;
        __syncthreads();
    }
    int excl = sofs[tid] - scnt[tid];
    sofs[tid] = excl;
    if (tid < NB && scnt[tid] > 0)
        gslot[tid] = rowptr[tid << shift] + atomicAdd(&gcur[tid], scnt[tid]);
    __syncthreads();
#pragma unroll
    for (int u = 0; u < 16; ++u) {
        if (eb[u] >= 0) {
            int idx = sofs[eb[u]] + eidx[u];      // no second atomic pass
            sdata[idx] = make_int2(epk[u], __float_as_int(ew[u]));
            sbkt[idx] = (unsigned short)eb[u];
        }
    }
    __syncthreads();
    int cntR = min(4096, E - base);
    for (int i = tid; i < cntR; i += 256) {
        int b = sbkt[i];
        epack_mid[gslot[b] + (i - sofs[b])] = sdata[i];
    }
}

// ---------------- pass C: within-bucket CSR placement ----------------
__global__ __launch_bounds__(256) void bucket_sort_kernel(
        const int* __restrict__ rowptr, const int2* __restrict__ epack_mid,
        int2* __restrict__ epack, int N, int shift) {
    __shared__ int lcur[4096];
    int b = blockIdx.x;
    int tid = threadIdx.x;
    int rows = 1 << shift;
    int row0 = b << shift;
    for (int j = tid; j < rows; j += 256) {
        int rid = row0 + j;
        if (rid < N) lcur[j] = rowptr[rid];
    }
    __syncthreads();
    int slice0 = rowptr[row0];
    int slice1 = rowptr[min(row0 + rows, N)];
    for (int i = slice0 + tid; i < slice1; i += 256) {
        int2 p = epack_mid[i];
        int rl = ((unsigned)p.x) >> 20;
        int pos = atomicAdd(&lcur[rl], 1);
        epack[pos] = make_int2(p.x & 0xFFFFF, p.y);
    }
}

// ---------------- CSR aggregation, D=128, fp16 in / fp16 out, relu ----------------
__global__ __launch_bounds__(256) void agg128_kernel(const __half2* __restrict__ H,
        const int* __restrict__ rowptr, const int2* __restrict__ epack,
        const float* __restrict__ wself, const float* __restrict__ bias,
        __half2* __restrict__ out, int n) {
    int node = blockIdx.x * 4 + (threadIdx.x >> 6);
    if (node >= n) return;
    int lane = threadIdx.x & 63;
    int start = rowptr[node], end = rowptr[node + 1];
    float ws = wself[node];
    float2 hs = __half22float2(H[(size_t)node * 64 + lane]);
    float ax = ws * hs.x, ay = ws * hs.y;
    int e = start;
    for (; e + 16 <= end; e += 16) {
        int2 p[16];
#pragma unroll
        for (int j = 0; j < 16; ++j) p[j] = epack[e + j];
        __half2 hh[16];
#pragma unroll
        for (int j = 0; j < 16; ++j) hh[j] = H[(size_t)p[j].x * 64 + lane];
#pragma unroll
        for (int j = 0; j < 16; ++j) {
            float w = __int_as_float(p[j].y);
            float2 f = __half22float2(hh[j]);
            ax += w * f.x; ay += w * f.y;
        }
    }
    if (e + 8 <= end) {
        int2 p[8];
#pragma unroll
        for (int j = 0; j < 8; ++j) p[j] = epack[e + j];
        __half2 hh[8];
#pragma unroll
        for (int j = 0; j < 8; ++j) hh[j] = H[(size_t)p[j].x * 64 + lane];
#pragma unroll
        for (int j = 0; j < 8; ++j) {
            float w = __int_as_float(p[j].y);
            float2 f = __half22float2(hh[j]);
            ax += w * f.x; ay += w * f.y;
        }
        e += 8;
    }
    if (e + 4 <= end) {
        int2 p[4];
#pragma unroll
        for (int j = 0; j < 4; ++j) p[j] = epack[e + j];
        __half2 hh[4];
#pragma unroll
        for (int j = 0; j < 4; ++j) hh[j] = H[(size_t)p[j].x * 64 + lane];
#pragma unroll
        for (int j = 0; j < 4; ++j) {
            float w = __int_as_float(p[j].y);
            float2 f = __half22float2(hh[j]);
            ax += w * f.x; ay += w * f.y;
        }
        e += 4;
    }
    for (; e < end; ++e) {
        int2 pe = epack[e];
        float w = __int_as_float(pe.y);
        float2 f = __half22float2(H[(size_t)pe.x * 64 + lane]);
        ax += w * f.x; ay += w * f.y;
    }
    float2 b = *(const float2*)&bias[2 * lane];
    float vx = fmaxf(ax + b.x, 0.0f);
    float vy = fmaxf(ay + b.y, 0.0f);
    out[(size_t)node * 64 + lane] = __floats2half2_rn(vx, vy);
}

// ---------------- CSR aggregation, D=64, fp16 in / fp32 out, no relu ----------------
__global__ __launch_bounds__(256) void agg64_kernel(const __half* __restrict__ H,
        const int* __restrict__ rowptr, const int2* __restrict__ epack,
        const float* __restrict__ wself, const float* __restrict__ bias,
        float* __restrict__ out, int n) {
    int node = blockIdx.x * 4 + (threadIdx.x >> 6);
    if (node >= n) return;
    int lane = threadIdx.x & 63;
    int start = rowptr[node], end = rowptr[node + 1];
    float ws = wself[node];
    float acc = ws * __half2float(H[(size_t)node * 64 + lane]);
    int e = start;
    for (; e + 16 <= end; e += 16) {
        int2 p[16];
#pragma unroll
        for (int j = 0; j < 16; ++j) p[j] = epack[e + j];
        float f[16];
#pragma unroll
        for (int j = 0; j < 16; ++j) f[j] = __half2float(H[(size_t)p[j].x * 64 + lane]);
#pragma unroll
        for (int j = 0; j < 16; ++j) acc += __int_as_float(p[j].y) * f[j];
    }
    if (e + 8 <= end) {
        int2 p[8];
#pragma unroll
        for (int j = 0; j < 8; ++j) p[j] = epack[e + j];
        float f[8];
#pragma unroll
        for (int j = 0; j < 8; ++j) f[j] = __half2float(H[(size_t)p[j].x * 64 + lane]);
#pragma unroll
        for (int j = 0; j < 8; ++j) acc += __int_as_float(p[j].y) * f[j];
        e += 8;
    }
    if (e + 4 <= end) {
        int2 p[4];
#pragma unroll
        for (int j = 0; j < 4; ++j) p[j] = epack[e + j];
        float f[4];
#pragma unroll
        for (int j = 0; j < 4; ++j) f[j] = __half2float(H[(size_t)p[j].x * 64 + lane]);
#pragma unroll
        for (int j = 0; j < 4; ++j) acc += __int_as_float(p[j].y) * f[j];
        e += 4;
    }
    for (; e < end; ++e) {
        int2 pe = epack[e];
        acc += __int_as_float(pe.y) * __half2float(H[(size_t)pe.x * 64 + lane]);
    }
    out[(size_t)node * 64 + lane] = acc + bias[lane];
}

// ---------------- launch ----------------
extern "C" void kernel_launch(void* const* d_in, const int* in_sizes, int n_in,
                              void* d_out, int out_size, void* d_ws, size_t ws_size,
                              hipStream_t stream) {
    const float* x  = (const float*)d_in[0];
    const int*   ei = (const int*)d_in[1];
    const float* W1 = (const float*)d_in[2];
    const float* b1 = (const float*)d_in[3];
    const float* W2 = (const float*)d_in[4];
    const float* b2 = (const float*)d_in[5];
    const float* W3 = (const float*)d_in[6];
    const float* b3 = (const float*)d_in[7];
    const float* p1 = (const float*)d_in[8];
    const float* p2 = (const float*)d_in[9];

    const int N = in_sizes[0] / 128;
    const int E = in_sizes[1] / 2;
    const int* row = ei;
    const int* col = ei + E;

    // bucket shift: smallest s with ((N-1)>>s)+1 <= 256  (N=100000 -> 9, 196 buckets)
    int shift = 0;
    while ((((N - 1) >> shift) + 1) > 256) shift++;
    const int NB = ((N - 1) >> shift) + 1;

    char* p = (char*)d_ws;
    auto alloc = [&](size_t bytes) -> void* {
        void* q = (void*)p;
        p += (bytes + 255) & ~(size_t)255;
        return q;
    };
    int*      degi      = (int*)alloc((size_t)N * 4);
    int*      gcur      = (int*)alloc(256 * 4);          // contiguous with degi for one memset
    int*      rowptr    = (int*)alloc((size_t)(N + 1) * 4);
    const int NBLK      = (N + 1023) / 1024;             // 98 (<=128 for scan_add inline top)
    int*      blocksum  = (int*)alloc((size_t)NBLK * 4);
    float4*   coeff     = (float4*)alloc((size_t)N * 16);
    float*    wself     = (float*)alloc((size_t)N * 4);
    int2*     epack_mid = (int2*)alloc((size_t)E * 8);
    int2*     epack     = (int2*)alloc((size_t)E * 8);
    _Float16* Wt2       = (_Float16*)alloc(128 * 128 * 2);
    _Float16* Wt3       = (_Float16*)alloc(128 * 64 * 2);
    _Float16* bufH      = (_Float16*)alloc((size_t)N * 128 * 2);
    _Float16* actH      = (_Float16*)alloc((size_t)N * 128 * 2);
    (void)ws_size; (void)n_in;

    size_t zero_bytes = (size_t)((char*)rowptr - (char*)degi);
    hipMemsetAsync(degi, 0, zero_bytes, stream);

    const int gemmGrid  = (N + 127) / 128;
    const int degBlocks4 = (E + 1023) / 1024;
    const int convBlocks = (24576 + 255) / 256;          // W2 (16384) + W3 (8192)
    // K1: gemm1 + deg count + W2/W3 convert, one dispatch (gemm blocks first)
    setup_fused_kernel<<<gemmGrid + degBlocks4 + convBlocks, 256, 0, stream>>>(
        x, W1, bufH, N, row, degi, E, W2, W3, Wt2, Wt3, gemmGrid, degBlocks4);

    scan_block_kernel<<<NBLK, 256, 0, stream>>>(degi, rowptr, blocksum, p1, p2, coeff, wself, N);
    scan_add_kernel<<<(N + 255) / 256, 256, 0, stream>>>(rowptr, blocksum, N, NBLK);
    partition_kernel<<<(E + 4095) / 4096, 256, 0, stream>>>(row, col, rowptr, gcur, coeff,
                                                            epack_mid, E, shift, NB);
    bucket_sort_kernel<<<NB, 256, 0, stream>>>(rowptr, epack_mid, epack, N, shift);

    float* out = (float*)d_out;
    int aggGrid = (N + 3) / 4;
    // layer 1 aggregation (gemm1 already done in K1)
    agg128_kernel<<<aggGrid, 256, 0, stream>>>((const __half2*)bufH, rowptr, epack, wself,
                                               b1, (__half2*)actH, N);
    // layer 2
    gemm_mfma<128><<<gemmGrid, 256, 0, stream>>>(actH, Wt2, bufH, N);
    agg128_kernel<<<aggGrid, 256, 0, stream>>>((const __half2*)bufH, rowptr, epack, wself,
                                               b2, (__half2*)actH, N);
    // layer 3 (D_OUT=64, no relu)
    gemm_mfma<64><<<gemmGrid, 256, 0, stream>>>(actH, Wt3, bufH, N);
    agg64_kernel<<<aggGrid, 256, 0, stream>>>((const __half*)bufH, rowptr, epack, wself,
                                              b3, out, N);
}

// Round 10
// 428.517 us; speedup vs baseline: 2.2287x; 1.1337x over previous
//
#include <hip/hip_runtime.h>
#include <hip/hip_fp16.h>
#include <math.h>
#include <type_traits>

typedef _Float16 half8 __attribute__((ext_vector_type(8)));
typedef float floatx4 __attribute__((ext_vector_type(4)));

#define RSHIFT 9          // rows per bucket = 512; NB = ceil(N/512) <= 256

// ---------------- K1: row-bucket histogram (LDS) + W convert ----------------
__global__ __launch_bounds__(256) void hist_conv_kernel(
        const int* __restrict__ row, int E, int* __restrict__ bucketsize,
        const float* __restrict__ W1, const float* __restrict__ W2,
        const float* __restrict__ W3, _Float16* __restrict__ Wt1,
        _Float16* __restrict__ Wt2, _Float16* __restrict__ Wt3, int histBlocks) {
    int tid = threadIdx.x;
    if ((int)blockIdx.x < histBlocks) {
        __shared__ int h[256];
        h[tid] = 0;
        __syncthreads();
        int base = blockIdx.x * 16384;
#pragma unroll
        for (int it = 0; it < 16; ++it) {
            int e0 = base + it * 1024 + tid * 4;
            if (e0 + 3 < E) {
                int4 r4 = *(const int4*)&row[e0];
                atomicAdd(&h[r4.x >> RSHIFT], 1);
                atomicAdd(&h[r4.y >> RSHIFT], 1);
                atomicAdd(&h[r4.z >> RSHIFT], 1);
                atomicAdd(&h[r4.w >> RSHIFT], 1);
            } else {
#pragma unroll
                for (int j = 0; j < 4; ++j)
                    if (e0 + j < E) atomicAdd(&h[row[e0 + j] >> RSHIFT], 1);
            }
        }
        __syncthreads();
        if (h[tid]) atomicAdd(&bucketsize[tid], h[tid]);
    } else {
        int g = ((int)blockIdx.x - histBlocks) * 256 + tid;
        if (g < 16384) {
            int k = g >> 7, n = g & 127;
            Wt1[n * 128 + k] = (_Float16)W1[g];
        } else if (g < 32768) {
            int h2 = g - 16384; int k = h2 >> 7, n = h2 & 127;
            Wt2[n * 128 + k] = (_Float16)W2[h2];
        } else if (g < 40960) {
            int h2 = g - 32768; int k = h2 >> 6, n = h2 & 63;
            Wt3[n * 128 + k] = (_Float16)W3[h2];
        }
    }
}

// ---------------- K2: scan bucket sizes -> bucketbase[0..256]; rowptr[N]=E ----------------
__global__ void scan_buckets_kernel(const int* __restrict__ bucketsize,
                                    int* __restrict__ bucketbase,
                                    int* __restrict__ rowptr, int N, int E) {
    __shared__ int s[256];
    int tid = threadIdx.x;
    int v = bucketsize[tid];
    s[tid] = v;
    __syncthreads();
    for (int off = 1; off < 256; off <<= 1) {
        int u = (tid >= off) ? s[tid - off] : 0;
        __syncthreads();
        s[tid] += u;
        __syncthreads();
    }
    bucketbase[tid] = s[tid] - v;
    if (tid == 255) bucketbase[256] = s[255];
    if (tid == 0) rowptr[N] = E;
}

// ---------------- K3: radix partition by row-bucket (no weights, 4B entries) ----------------
__global__ __launch_bounds__(256) void partition_kernel(
        const int* __restrict__ row, const int* __restrict__ col,
        const int* __restrict__ bucketbase, int* __restrict__ gcur,
        int* __restrict__ emid, int E, int NB) {
    __shared__ int scnt[256], sofs[256], gslot[256];
    __shared__ int sdata[4096];
    __shared__ unsigned short sbkt[4096];

    int tid = threadIdx.x;
    int base = blockIdx.x * 4096;
    scnt[tid] = 0;
    __syncthreads();

    int epk[16]; int eb[16]; int eidx[16];
#pragma unroll
    for (int v = 0; v < 4; ++v) {
        int e0 = base + v * 1024 + tid * 4;
        int4 r4, c4;
        bool full = (e0 + 3 < E);
        if (full) {
            r4 = *(const int4*)&row[e0];
            c4 = *(const int4*)&col[e0];
        }
#pragma unroll
        for (int j = 0; j < 4; ++j) {
            int u = v * 4 + j;
            eb[u] = -1;
            int r, c;
            if (full) {
                r = (&r4.x)[j]; c = (&c4.x)[j];
            } else {
                if (e0 + j >= E) continue;
                r = row[e0 + j]; c = col[e0 + j];
            }
            int b = r >> RSHIFT;
            eb[u] = b;
            eidx[u] = atomicAdd(&scnt[b], 1);
            epk[u] = c | ((r & ((1 << RSHIFT) - 1)) << 20);
        }
    }
    __syncthreads();
    sofs[tid] = scnt[tid];
    __syncthreads();
    for (int off = 1; off < 256; off <<= 1) {
        int v = (tid >= off) ? sofs[tid - off] : 0;
        __syncthreads();
        sofs[tid] += v;
        __syncthreads();
    }
    int excl = sofs[tid] - scnt[tid];
    sofs[tid] = excl;
    if (tid < NB && scnt[tid] > 0)
        gslot[tid] = bucketbase[tid] + atomicAdd(&gcur[tid], scnt[tid]);
    __syncthreads();
#pragma unroll
    for (int u = 0; u < 16; ++u) {
        if (eb[u] >= 0) {
            int idx = sofs[eb[u]] + eidx[u];
            sdata[idx] = epk[u];
            sbkt[idx] = (unsigned short)eb[u];
        }
    }
    __syncthreads();
    int cntR = min(4096, E - base);
    for (int i = tid; i < cntR; i += 256) {
        int b = sbkt[i];
        emid[gslot[b] + (i - sofs[b])] = sdata[i];
    }
}

// ---------------- K4: per-bucket degree count (LDS atomics) + rowptr slice ----------------
__global__ __launch_bounds__(256) void bucket_deg_kernel(
        const int* __restrict__ bucketbase, const int* __restrict__ emid,
        int* __restrict__ rowptr, int N) {
    __shared__ int cnt[512];
    __shared__ int ssum[256];
    int b = blockIdx.x;
    int tid = threadIdx.x;
    int row0 = b << RSHIFT;
    int nrows = min(512, N - row0);
    cnt[tid] = 0; cnt[tid + 256] = 0;
    __syncthreads();
    int seg0 = bucketbase[b], seg1 = bucketbase[b + 1];
    for (int i = seg0 + tid; i < seg1; i += 256)
        atomicAdd(&cnt[((unsigned)emid[i]) >> 20], 1);
    __syncthreads();
    int a0 = cnt[2 * tid], a1 = cnt[2 * tid + 1];
    int tsum = a0 + a1;
    ssum[tid] = tsum;
    __syncthreads();
    for (int off = 1; off < 256; off <<= 1) {
        int v = (tid >= off) ? ssum[tid - off] : 0;
        __syncthreads();
        ssum[tid] += v;
        __syncthreads();
    }
    int excl = ssum[tid] - tsum;
    if (2 * tid < nrows)     rowptr[row0 + 2 * tid]     = seg0 + excl;
    if (2 * tid + 1 < nrows) rowptr[row0 + 2 * tid + 1] = seg0 + excl + a0;
}

// ---------------- GSO coefficients from rowptr diffs ----------------
__device__ __forceinline__ float pow_z(float d, float e) {
    float p = powf(d, e);
    return isinf(p) ? 0.0f : p;   // reference zeroes inf from 0**negative
}

__global__ void node_coeff_kernel(const int* __restrict__ rowptr,
                                  const float* __restrict__ p1, const float* __restrict__ p2,
                                  float4* __restrict__ coeff, float* __restrict__ wself, int N) {
    int g = blockIdx.x * blockDim.x + threadIdx.x;
    if (g >= N) return;
    float deg = (float)(rowptr[g + 1] - rowptr[g]);
    float m1a = p1[0], m2a = p1[1], m3a = p1[2], e1a = p1[3], e2a = p1[4], e3a = p1[5], aa = p1[6];
    float m1b = p2[0], m2b = p2[1], m3b = p2[2], e1b = p2[3], e2b = p2[4], e3b = p2[5], ab = p2[6];
    float d1 = deg + aa, d2 = deg + ab;
    float pa1 = pow_z(d1, e1a), pa2 = pow_z(d1, e2a), pa3 = pow_z(d1, e3a);
    float pb1 = pow_z(d2, e1b), pb2 = pow_z(d2, e2b), pb3 = pow_z(d2, e3b);
    coeff[g] = make_float4(m2a * pa2, pa3, m2b * pb2, pb3);
    wself[g] = m1a * pa1 + m2a * pa2 * pa3 + m3a
             + m1b * pb1 + m2b * pb2 * pb3 + m3b;
}

// ---------------- K6: per-bucket weight compute + final CSR placement ----------------
__global__ __launch_bounds__(256) void bucket_place_kernel(
        const int* __restrict__ bucketbase, const int* __restrict__ emid,
        const int* __restrict__ rowptr, const float4* __restrict__ coeff,
        int2* __restrict__ epack, int N) {
    __shared__ int lcur[512];
    __shared__ float4 scoef[512];
    int b = blockIdx.x;
    int tid = threadIdx.x;
    int row0 = b << RSHIFT;
    int nrows = min(512, N - row0);
#pragma unroll
    for (int u = 0; u < 2; ++u) {
        int j = tid + u * 256;
        if (j < nrows) {
            lcur[j] = rowptr[row0 + j];
            scoef[j] = coeff[row0 + j];
        }
    }
    __syncthreads();
    int seg0 = bucketbase[b], seg1 = bucketbase[b + 1];
    for (int i = seg0 + tid; i < seg1; i += 256) {
        int v = emid[i];
        int rl = ((unsigned)v) >> 20;
        int c = v & 0xFFFFF;
        float4 cr = scoef[rl];
        float4 cc = coeff[c];
        float w = cr.x * cc.y + cr.z * cc.w;
        int pos = atomicAdd(&lcur[rl], 1);
        epack[pos] = make_int2(c, __float_as_int(w));
    }
}

// ---------------- MFMA GEMM: A[n x 128] @ Wt[TN x 128] -> C[n x TN] fp16 ----------------
template<int TN, typename AT>
__global__ __launch_bounds__(256) void gemm_mfma(const AT* __restrict__ A,
        const _Float16* __restrict__ Wt, _Float16* __restrict__ C, int n) {
    constexpr int K = 128;
    constexpr int TM = 128;
    constexpr int LDK = K + 8;
    __shared__ _Float16 As[TM][LDK];
    __shared__ _Float16 Bs[TN][LDK];

    int tid = threadIdx.x;
    int wave = tid >> 6, lane = tid & 63;
    int q = lane >> 4, t = lane & 15;
    int rowbase = blockIdx.x * TM;

    if constexpr (std::is_same<AT, float>::value) {
        for (int i = tid; i < TM * K / 4; i += 256) {
            int r = i >> 5;
            int kc = (i & 31) * 4;
            int rr = rowbase + r;
            float4 v = make_float4(0.f, 0.f, 0.f, 0.f);
            if (rr < n) v = *(const float4*)&A[(size_t)rr * K + kc];
            As[r][kc + 0] = (_Float16)v.x;
            As[r][kc + 1] = (_Float16)v.y;
            As[r][kc + 2] = (_Float16)v.z;
            As[r][kc + 3] = (_Float16)v.w;
        }
    } else {
        for (int i = tid; i < TM * K / 8; i += 256) {
            int r = i >> 4;
            int kc = (i & 15) * 8;
            int rr = rowbase + r;
            uint4 v = make_uint4(0u, 0u, 0u, 0u);
            if (rr < n) v = *(const uint4*)&A[(size_t)rr * K + kc];
            *(uint4*)&As[r][kc] = v;
        }
    }
    for (int i = tid; i < TN * K / 8; i += 256) {
        int nr = i >> 4;
        int kc = (i & 15) * 8;
        *(uint4*)&Bs[nr][kc] = *(const uint4*)&Wt[(size_t)nr * K + kc];
    }
    __syncthreads();

    int m0 = wave * 32;
    floatx4 acc0[TN / 16], acc1[TN / 16];
#pragma unroll
    for (int nt = 0; nt < TN / 16; ++nt) {
        acc0[nt] = (floatx4){0.f, 0.f, 0.f, 0.f};
        acc1[nt] = (floatx4){0.f, 0.f, 0.f, 0.f};
    }

#pragma unroll
    for (int kk = 0; kk < K; kk += 32) {
        half8 a0 = *(const half8*)&As[m0 + t][kk + q * 8];
        half8 a1 = *(const half8*)&As[m0 + 16 + t][kk + q * 8];
#pragma unroll
        for (int nt = 0; nt < TN / 16; ++nt) {
            half8 b = *(const half8*)&Bs[nt * 16 + t][kk + q * 8];
            acc0[nt] = __builtin_amdgcn_mfma_f32_16x16x32_f16(a0, b, acc0[nt], 0, 0, 0);
            acc1[nt] = __builtin_amdgcn_mfma_f32_16x16x32_f16(a1, b, acc1[nt], 0, 0, 0);
        }
    }

#pragma unroll
    for (int nt = 0; nt < TN / 16; ++nt) {
#pragma unroll
        for (int r = 0; r < 4; ++r) {
            int rr0 = rowbase + m0 + q * 4 + r;
            if (rr0 < n) C[(size_t)rr0 * TN + nt * 16 + t] = (_Float16)acc0[nt][r];
            int rr1 = rr0 + 16;
            if (rr1 < n) C[(size_t)rr1 * TN + nt * 16 + t] = (_Float16)acc1[nt][r];
        }
    }
}

// ---------------- CSR aggregation, D=128, fp16 in / fp16 out, relu ----------------
__global__ __launch_bounds__(256) void agg128_kernel(const __half2* __restrict__ H,
        const int* __restrict__ rowptr, const int2* __restrict__ epack,
        const float* __restrict__ wself, const float* __restrict__ bias,
        __half2* __restrict__ out, int n) {
    int node = blockIdx.x * 4 + (threadIdx.x >> 6);
    if (node >= n) return;
    int lane = threadIdx.x & 63;
    int start = rowptr[node], end = rowptr[node + 1];
    float ws = wself[node];
    float2 hs = __half22float2(H[(size_t)node * 64 + lane]);
    float ax = ws * hs.x, ay = ws * hs.y;
    int e = start;
    for (; e + 16 <= end; e += 16) {
        int2 p[16];
#pragma unroll
        for (int j = 0; j < 16; ++j) p[j] = epack[e + j];
        __half2 hh[16];
#pragma unroll
        for (int j = 0; j < 16; ++j) hh[j] = H[(size_t)p[j].x * 64 + lane];
#pragma unroll
        for (int j = 0; j < 16; ++j) {
            float w = __int_as_float(p[j].y);
            float2 f = __half22float2(hh[j]);
            ax += w * f.x; ay += w * f.y;
        }
    }
    if (e + 8 <= end) {
        int2 p[8];
#pragma unroll
        for (int j = 0; j < 8; ++j) p[j] = epack[e + j];
        __half2 hh[8];
#pragma unroll
        for (int j = 0; j < 8; ++j) hh[j] = H[(size_t)p[j].x * 64 + lane];
#pragma unroll
        for (int j = 0; j < 8; ++j) {
            float w = __int_as_float(p[j].y);
            float2 f = __half22float2(hh[j]);
            ax += w * f.x; ay += w * f.y;
        }
        e += 8;
    }
    if (e + 4 <= end) {
        int2 p[4];
#pragma unroll
        for (int j = 0; j < 4; ++j) p[j] = epack[e + j];
        __half2 hh[4];
#pragma unroll
        for (int j = 0; j < 4; ++j) hh[j] = H[(size_t)p[j].x * 64 + lane];
#pragma unroll
        for (int j = 0; j < 4; ++j) {
            float w = __int_as_float(p[j].y);
            float2 f = __half22float2(hh[j]);
            ax += w * f.x; ay += w * f.y;
        }
        e += 4;
    }
    for (; e < end; ++e) {
        int2 pe = epack[e];
        float w = __int_as_float(pe.y);
        float2 f = __half22float2(H[(size_t)pe.x * 64 + lane]);
        ax += w * f.x; ay += w * f.y;
    }
    float2 b = *(const float2*)&bias[2 * lane];
    float vx = fmaxf(ax + b.x, 0.0f);
    float vy = fmaxf(ay + b.y, 0.0f);
    out[(size_t)node * 64 + lane] = __floats2half2_rn(vx, vy);
}

// ---------------- CSR aggregation, D=64, fp16 in / fp32 out, no relu ----------------
__global__ __launch_bounds__(256) void agg64_kernel(const __half* __restrict__ H,
        const int* __restrict__ rowptr, const int2* __restrict__ epack,
        const float* __restrict__ wself, const float* __restrict__ bias,
        float* __restrict__ out, int n) {
    int node = blockIdx.x * 4 + (threadIdx.x >> 6);
    if (node >= n) return;
    int lane = threadIdx.x & 63;
    int start = rowptr[node], end = rowptr[node + 1];
    float ws = wself[node];
    float acc = ws * __half2float(H[(size_t)node * 64 + lane]);
    int e = start;
    for (; e + 16 <= end; e += 16) {
        int2 p[16];
#pragma unroll
        for (int j = 0; j < 16; ++j) p[j] = epack[e + j];
        float f[16];
#pragma unroll
        for (int j = 0; j < 16; ++j) f[j] = __half2float(H[(size_t)p[j].x * 64 + lane]);
#pragma unroll
        for (int j = 0; j < 16; ++j) acc += __int_as_float(p[j].y) * f[j];
    }
    if (e + 8 <= end) {
        int2 p[8];
#pragma unroll
        for (int j = 0; j < 8; ++j) p[j] = epack[e + j];
        float f[8];
#pragma unroll
        for (int j = 0; j < 8; ++j) f[j] = __half2float(H[(size_t)p[j].x * 64 + lane]);
#pragma unroll
        for (int j = 0; j < 8; ++j) acc += __int_as_float(p[j].y) * f[j];
        e += 8;
    }
    if (e + 4 <= end) {
        int2 p[4];
#pragma unroll
        for (int j = 0; j < 4; ++j) p[j] = epack[e + j];
        float f[4];
#pragma unroll
        for (int j = 0; j < 4; ++j) f[j] = __half2float(H[(size_t)p[j].x * 64 + lane]);
#pragma unroll
        for (int j = 0; j < 4; ++j) acc += __int_as_float(p[j].y) * f[j];
        e += 4;
    }
    for (; e < end; ++e) {
        int2 pe = epack[e];
        acc += __int_as_float(pe.y) * __half2float(H[(size_t)pe.x * 64 + lane]);
    }
    out[(size_t)node * 64 + lane] = acc + bias[lane];
}

// ---------------- launch ----------------
extern "C" void kernel_launch(void* const* d_in, const int* in_sizes, int n_in,
                              void* d_out, int out_size, void* d_ws, size_t ws_size,
                              hipStream_t stream) {
    const float* x  = (const float*)d_in[0];
    const int*   ei = (const int*)d_in[1];
    const float* W1 = (const float*)d_in[2];
    const float* b1 = (const float*)d_in[3];
    const float* W2 = (const float*)d_in[4];
    const float* b2 = (const float*)d_in[5];
    const float* W3 = (const float*)d_in[6];
    const float* b3 = (const float*)d_in[7];
    const float* p1 = (const float*)d_in[8];
    const float* p2 = (const float*)d_in[9];

    const int N = in_sizes[0] / 128;
    const int E = in_sizes[1] / 2;
    const int* row = ei;
    const int* col = ei + E;
    const int NB = ((N - 1) >> RSHIFT) + 1;      // 196 buckets for N=100000

    char* p = (char*)d_ws;
    auto alloc = [&](size_t bytes) -> void* {
        void* q = (void*)p;
        p += (bytes + 255) & ~(size_t)255;
        return q;
    };
    int*      bucketsize = (int*)alloc(256 * 4);
    int*      gcur       = (int*)alloc(256 * 4);         // contiguous with bucketsize: one memset
    int*      bucketbase = (int*)alloc(257 * 4);
    int*      rowptr     = (int*)alloc((size_t)(N + 1) * 4);
    float4*   coeff      = (float4*)alloc((size_t)N * 16);
    float*    wself      = (float*)alloc((size_t)N * 4);
    int*      emid       = (int*)alloc((size_t)E * 4);
    int2*     epack      = (int2*)alloc((size_t)E * 8);
    _Float16* Wt1        = (_Float16*)alloc(128 * 128 * 2);
    _Float16* Wt2        = (_Float16*)alloc(128 * 128 * 2);
    _Float16* Wt3        = (_Float16*)alloc(128 * 64 * 2);
    _Float16* bufH       = (_Float16*)alloc((size_t)N * 128 * 2);
    _Float16* actH       = (_Float16*)alloc((size_t)N * 128 * 2);
    (void)ws_size; (void)n_in;

    hipMemsetAsync(bucketsize, 0, 512 * 4, stream);      // bucketsize + gcur

    const int histBlocks = (E + 16383) / 16384;          // 98
    const int convBlocks = (40960 + 255) / 256;          // 160
    hist_conv_kernel<<<histBlocks + convBlocks, 256, 0, stream>>>(
        row, E, bucketsize, W1, W2, W3, Wt1, Wt2, Wt3, histBlocks);
    scan_buckets_kernel<<<1, 256, 0, stream>>>(bucketsize, bucketbase, rowptr, N, E);
    partition_kernel<<<(E + 4095) / 4096, 256, 0, stream>>>(row, col, bucketbase, gcur,
                                                            emid, E, NB);
    bucket_deg_kernel<<<NB, 256, 0, stream>>>(bucketbase, emid, rowptr, N);
    node_coeff_kernel<<<(N + 255) / 256, 256, 0, stream>>>(rowptr, p1, p2, coeff, wself, N);
    bucket_place_kernel<<<NB, 256, 0, stream>>>(bucketbase, emid, rowptr, coeff, epack, N);

    float* out = (float*)d_out;
    int aggGrid = (N + 3) / 4;
    int gemmGrid = (N + 127) / 128;
    // layer 1
    gemm_mfma<128, float><<<gemmGrid, 256, 0, stream>>>(x, Wt1, bufH, N);
    agg128_kernel<<<aggGrid, 256, 0, stream>>>((const __half2*)bufH, rowptr, epack, wself,
                                               b1, (__half2*)actH, N);
    // layer 2
    gemm_mfma<128, _Float16><<<gemmGrid, 256, 0, stream>>>(actH, Wt2, bufH, N);
    agg128_kernel<<<aggGrid, 256, 0, stream>>>((const __half2*)bufH, rowptr, epack, wself,
                                               b2, (__half2*)actH, N);
    // layer 3 (D_OUT=64, no relu)
    gemm_mfma<64, _Float16><<<gemmGrid, 256, 0, stream>>>(actH, Wt3, bufH, N);
    agg64_kernel<<<aggGrid, 256, 0, stream>>>((const __half*)bufH, rowptr, epack, wself,
                                              b3, out, N);
}